// Round 7
// baseline (255.826 us; speedup 1.0000x reference)
//
#include <hip/hip_runtime.h>
#include <math.h>

typedef __attribute__((ext_vector_type(8))) short short8;
typedef __attribute__((ext_vector_type(4))) float float4v;
typedef __attribute__((ext_vector_type(4))) unsigned short ushort4v;

static __device__ __forceinline__ unsigned short f2bf(float f) {
    union { float f; unsigned u; } v; v.f = f;
    unsigned u = v.u;
    return (unsigned short)((u + 0x7fffu + ((u >> 16) & 1u)) >> 16);
}
static __device__ __forceinline__ float bf2f(unsigned short h) {
    union { unsigned u; float f; } v; v.u = ((unsigned)h) << 16;
    return v.f;
}

// ---------------------------------------------------------------------------
// Graph structure (compile-time), matching Python enumeration order.
// ---------------------------------------------------------------------------
struct AdjT {
    int src[120];
    int dst[120];
    int cnt[36];
    int idx[36][4];    // incoming edges per node
    int ostart[36];    // outgoing edge run start
    int ocnt[36];      // outgoing edge run length
};

constexpr AdjT build_adj() {
    AdjT a{};
    const int ddx[4] = {-1, 0, 0, 1};
    const int ddy[4] = {0, -1, 1, 0};
    int ne = 0;
    for (int i = 0; i < 6; i++)
        for (int j = 0; j < 6; j++)
            for (int d = 0; d < 4; d++) {
                int x = i + ddx[d], y = j + ddy[d];
                if (x >= 0 && x < 6 && y >= 0 && y < 6) {
                    a.src[ne] = j * 6 + i;
                    a.dst[ne] = y * 6 + x;
                    ne++;
                }
            }
    for (int n = 0; n < 36; n++) {
        a.cnt[n] = 0;
        for (int e = 0; e < 120; e++)
            if (a.dst[e] == n) a.idx[n][a.cnt[n]++] = e;
    }
    for (int n = 0; n < 36; n++) { a.ostart[n] = 0; a.ocnt[n] = 0; }
    for (int e = 0; e < 120; e++) {
        a.ocnt[a.src[e]]++;
        if (e == 0 || a.src[e] != a.src[e - 1]) a.ostart[a.src[e]] = e;
    }
    return a;
}

__device__ constexpr AdjT ADJC = build_adj();
__device__ constexpr int G16_START[17] =
    {0, 3, 6, 9, 12, 14, 16, 18, 20, 22, 24, 26, 28, 30, 32, 34, 36};

// ---------------------------------------------------------------------------
// K0: weight prep — B-fragments (bf16) for conv2/conv3/conv4 MFMA.
// ---------------------------------------------------------------------------
__global__ __launch_bounds__(256) void k_prep(const float* __restrict__ w2,
                                              const float* __restrict__ w3,
                                              const float* __restrict__ w4,
                                              unsigned short* __restrict__ wp2,
                                              unsigned short* __restrict__ wp3,
                                              unsigned short* __restrict__ wp4) {
    int e = blockIdx.x * 256 + threadIdx.x;
    if (e < 25600) {
        int j = e & 7, lane = (e >> 3) & 63, ct = (e >> 9) & 1, t = e >> 10;
        int co = ct * 16 + (lane & 15), ci = (lane >> 4) * 8 + j;
        wp2[e] = f2bf(w2[co * 800 + ci * 25 + t]);
    } else if (e < 76800) {
        int e3 = e - 25600;
        int j = e3 & 7, lane = (e3 >> 3) & 63, nt = (e3 >> 9) & 3, t = e3 >> 11;
        int co = nt * 16 + (lane & 15), ci = (lane >> 4) * 8 + j;
        wp3[e3] = f2bf(w3[(co * 32 + ci) * 25 + t]);
    } else {
        int e4 = e - 76800;
        int j = e4 & 7, lane = (e4 >> 3) & 63, nt = (e4 >> 9) & 3;
        int ks = (e4 >> 11) & 1, t = e4 >> 12;
        int co = nt * 16 + (lane & 15), ci = ks * 32 + (lane >> 4) * 8 + j;
        wp4[e4] = f2bf(w4[(co * 64 + ci) * 25 + t]);
    }
}

// ---------------------------------------------------------------------------
// K0b: weight prep for heads MFMA (verified R4).
// ---------------------------------------------------------------------------
__global__ __launch_bounds__(256) void k_prep2(const float* __restrict__ cnw1,
                                               const float* __restrict__ epw1,
                                               const float* __restrict__ cnw2,
                                               const float* __restrict__ epw2,
                                               unsigned short* __restrict__ wph1,
                                               unsigned short* __restrict__ wpcn2,
                                               unsigned short* __restrict__ wpep2) {
    int e = blockIdx.x * 256 + threadIdx.x;
    if (e < 131072) {
        int j = e & 7, lane = (e >> 3) & 63, nt = (e >> 9) & 31, kt = e >> 14;
        int c = nt * 16 + (lane & 15);
        int k = kt * 32 + ((lane >> 4) << 3) + j;
        float v = (c < 256) ? cnw1[c * 256 + k] : epw1[(c - 256) * 256 + k];
        wph1[e] = f2bf(v);
    } else if (e < 163840) {
        int e2 = e - 131072;
        int j = e2 & 7, lane = (e2 >> 3) & 63, nt = (e2 >> 9) & 7, kt = e2 >> 12;
        int c = nt * 16 + (lane & 15);
        int k = kt * 32 + ((lane >> 4) << 3) + j;
        wpcn2[e2] = f2bf(c < 120 ? cnw2[c * 256 + k] : 0.f);
    } else {
        int e3 = e - 163840;
        int j = e3 & 7, lane = (e3 >> 3) & 63, idx = e3 >> 9;
        int kt = idx / 3, nt = idx - kt * 3;
        int c = nt * 16 + (lane & 15);
        int k = kt * 32 + ((lane >> 4) << 3) + j;
        wpep2[e3] = f2bf(c < 36 ? epw2[c * 256 + k] : 0.f);
    }
}

// ---------------------------------------------------------------------------
// K12: FUSED conv1 + conv2 + maxpool2.
// Block = half image (grid B*2), 128 threads (2 waves).
//  Phase A (conv1, VALU) — R7 rewrite, register-lean: position-per-lane
//    (p = pp*128+tid, 4 sweeps), 5x5 window in 25 regs (lane-consecutive
//    s_img reads = conflict-free), per channel-pair immediate packed-b32
//    LDS write (no res[] array -> no spills; 8 bank-start classes not 2).
//  Phase B (conv2, MFMA): verified R5 tap-GEMM on s_buf; stage/pool epilogue
//    unioned onto s_buf; out = p2 ch-last bf16 [144][32].
// ---------------------------------------------------------------------------
__global__ __launch_bounds__(128) void k_conv12(const float* __restrict__ img,
                                                const float* __restrict__ w1,
                                                const float* __restrict__ b1,
                                                const unsigned short* __restrict__ wprep,
                                                const float* __restrict__ bias2,
                                                unsigned short* __restrict__ out) {
    __shared__ float s_img[20 * 36];            // 20 rows x 32 cols, stride 36
    __shared__ unsigned short s_buf[448 * 40];  // conv1 out [448][40]; later stage [288][40]
    const int blk = blockIdx.x;
    const int b = blk >> 1, half = blk & 1;
    const int tid = threadIdx.x;
    const int lane = tid & 63, wave = tid >> 6;
    const int m = lane & 15, quad = lane >> 4;

    // stage image rows half*12 .. half*12+19 (640 floats = 160 float4)
    {
        const float4* g4 = (const float4*)(img + (size_t)b * 1024 + half * 12 * 32);
        for (int v = tid; v < 160; v += 128) {
            float4 t = g4[v];
            *(float4*)(s_img + (v >> 3) * 36 + (v & 7) * 4) = t;
        }
    }

    // conv2 B-frag prefetch (global, no LDS dependency)
    const short8* wp = (const short8*)wprep;
    short8 bw0 = wp[lane];
    short8 bw1 = wp[64 + lane];

    __syncthreads();

    // ---- phase A: conv1, position-per-lane ----
    for (int pp = 0; pp < 4; pp++) {
        const int p = pp * 128 + tid;
        if (p < 448) {
            const int y = p / 28, x = p - y * 28;
            float win[25];
#pragma unroll
            for (int r = 0; r < 5; r++)
#pragma unroll
                for (int c = 0; c < 5; c++)
                    win[r * 5 + c] = s_img[(y + r) * 36 + x + c];
            unsigned* dst = (unsigned*)(s_buf + p * 40);
#pragma unroll 2
            for (int cp = 0; cp < 16; cp++) {
                float a0 = b1[2 * cp], a1 = b1[2 * cp + 1];
                const float* w0 = w1 + 2 * cp * 25;
#pragma unroll
                for (int k = 0; k < 25; k++) {
                    a0 += win[k] * w0[k];
                    a1 += win[k] * w0[25 + k];
                }
                dst[cp] = (unsigned)f2bf(a0) | ((unsigned)f2bf(a1) << 16);
            }
        }
    }
    __syncthreads();

    // ---- phase B: conv2 tap-GEMM (verified R5 structure) ----
    int a_idx[9];
#pragma unroll
    for (int mt = 0; mt < 9; mt++) {
        int p = wave * 144 + mt * 16 + m;
        int yl = p / 24;
        int x = p - yl * 24;
        a_idx[mt] = (yl * 28 + x) * 40 + quad * 8;
    }

    float4v acc[9][2];
#pragma unroll
    for (int mt = 0; mt < 9; mt++) {
        acc[mt][0] = (float4v){0.f, 0.f, 0.f, 0.f};
        acc[mt][1] = (float4v){0.f, 0.f, 0.f, 0.f};
    }

    for (int t = 0; t < 25; t++) {
        short8 nb0, nb1;
        if (t < 24) {
            nb0 = wp[(t + 1) * 128 + lane];
            nb1 = wp[(t + 1) * 128 + 64 + lane];
        }
        const int ky = t / 5, kx = t - ky * 5;
        const int toff = (ky * 28 + kx) * 40;
#pragma unroll
        for (int mt = 0; mt < 9; mt++) {
            short8 av = *(const short8*)(s_buf + a_idx[mt] + toff);
            acc[mt][0] = __builtin_amdgcn_mfma_f32_16x16x32_bf16(av, bw0, acc[mt][0], 0, 0, 0);
            acc[mt][1] = __builtin_amdgcn_mfma_f32_16x16x32_bf16(av, bw1, acc[mt][1], 0, 0, 0);
        }
        if (t < 24) { bw0 = nb0; bw1 = nb1; }
    }

    __syncthreads();  // all A-reads done before stage overwrites s_buf

    const int n = lane & 15;
#pragma unroll
    for (int mt = 0; mt < 9; mt++) {
        int pbase = wave * 144 + mt * 16 + quad * 4;
#pragma unroll
        for (int r = 0; r < 4; r++) {
            s_buf[(pbase + r) * 40 + n] = f2bf(acc[mt][0][r]);
            s_buf[(pbase + r) * 40 + 16 + n] = f2bf(acc[mt][1][r]);
        }
    }
    __syncthreads();

    unsigned short* op = out + (size_t)b * 4608;
    for (int i = tid; i < 2304; i += 128) {
        int co = i & 31;
        int pos = i >> 5;
        int prl = pos / 12;
        int px = pos - prl * 12;
        int base = ((prl * 2) * 24 + px * 2) * 40 + co;
        float v0 = bf2f(s_buf[base]);
        float v1 = bf2f(s_buf[base + 40]);
        float v2 = bf2f(s_buf[base + 24 * 40]);
        float v3 = bf2f(s_buf[base + 25 * 40]);
        float mx = fmaxf(fmaxf(v0, v1), fmaxf(v2, v3));
        op[((half * 6 + prl) * 12 + px) * 32 + co] = f2bf(mx + bias2[co]);
    }
}

// ---------------------------------------------------------------------------
// K34: fused conv3 + conv4 + pool + flatten via MFMA tap-GEMM (verified R3-R6).
// ---------------------------------------------------------------------------
__global__ __launch_bounds__(64) void k_conv34(const unsigned short* __restrict__ p2,
                                               const unsigned short* __restrict__ wp3,
                                               const float* __restrict__ b3,
                                               const unsigned short* __restrict__ wp4,
                                               const float* __restrict__ b4,
                                               unsigned short* __restrict__ emb) {
    __shared__ unsigned short s_buf34[9216];  // s_in [0,4608) | s_c3 [4608,9216)
    unsigned short* s_in = s_buf34;
    unsigned short* s_c3 = s_buf34 + 4608;    // [64][72] padded
    float* s_c4 = (float*)s_buf34;            // [16][64] — reuses s_in region
    const int b = blockIdx.x, tid = threadIdx.x;
    const int m = tid & 15, q = tid >> 4;

    {
        const short8* g8 = (const short8*)(p2 + (size_t)b * 4608);
        short8* s8 = (short8*)s_in;
        for (int i = tid; i < 576; i += 64) s8[i] = g8[i];
    }

    int a_base[4];
#pragma unroll
    for (int mt = 0; mt < 4; mt++) {
        int p = mt * 16 + m;
        int y = p >> 3, x = p & 7;
        a_base[mt] = (y * 12 + x) * 32 + q * 8;
    }

    float4v acc3[4][4];
#pragma unroll
    for (int mt = 0; mt < 4; mt++)
#pragma unroll
        for (int nt = 0; nt < 4; nt++) acc3[mt][nt] = (float4v){0.f, 0.f, 0.f, 0.f};

    const short8* wp = (const short8*)wp3;
    short8 bw[4];
#pragma unroll
    for (int nt = 0; nt < 4; nt++) bw[nt] = wp[nt * 64 + tid];

    __syncthreads();

    for (int t = 0; t < 25; t++) {
        short8 nb[4];
        if (t < 24) {
#pragma unroll
            for (int nt = 0; nt < 4; nt++) nb[nt] = wp[((t + 1) * 4 + nt) * 64 + tid];
        }
        const int ky = t / 5, kx = t - ky * 5;
        const int toff = (ky * 12 + kx) * 32;
#pragma unroll
        for (int mt = 0; mt < 4; mt++) {
            short8 av = *(const short8*)(s_in + a_base[mt] + toff);
#pragma unroll
            for (int nt = 0; nt < 4; nt++)
                acc3[mt][nt] = __builtin_amdgcn_mfma_f32_16x16x32_bf16(av, bw[nt], acc3[mt][nt], 0, 0, 0);
        }
        if (t < 24) {
#pragma unroll
            for (int nt = 0; nt < 4; nt++) bw[nt] = nb[nt];
        }
    }

    {
        float bb[4];
#pragma unroll
        for (int nt = 0; nt < 4; nt++) bb[nt] = b3[nt * 16 + m];
#pragma unroll
        for (int mt = 0; mt < 4; mt++)
#pragma unroll
            for (int nt = 0; nt < 4; nt++)
#pragma unroll
                for (int r = 0; r < 4; r++)
                    s_c3[(mt * 16 + q * 4 + r) * 72 + nt * 16 + m] =
                        f2bf(acc3[mt][nt][r] + bb[nt]);
    }
    __syncthreads();

    const int a4_base = ((m >> 2) * 8 + (m & 3)) * 72 + q * 8;
    float4v acc4[4];
#pragma unroll
    for (int nt = 0; nt < 4; nt++) acc4[nt] = (float4v){0.f, 0.f, 0.f, 0.f};

    const short8* wq = (const short8*)wp4;
    short8 cw[8];
#pragma unroll
    for (int i = 0; i < 8; i++) cw[i] = wq[i * 64 + tid];

    for (int t = 0; t < 25; t++) {
        short8 nb[8];
        if (t < 24) {
#pragma unroll
            for (int i = 0; i < 8; i++) nb[i] = wq[((t + 1) * 8 + i) * 64 + tid];
        }
        const int ky = t / 5, kx = t - ky * 5;
        const int toff = (ky * 8 + kx) * 72;
#pragma unroll
        for (int ks = 0; ks < 2; ks++) {
            short8 av = *(const short8*)(s_c3 + a4_base + toff + ks * 32);
#pragma unroll
            for (int nt = 0; nt < 4; nt++)
                acc4[nt] = __builtin_amdgcn_mfma_f32_16x16x32_bf16(av, cw[ks * 4 + nt], acc4[nt], 0, 0, 0);
        }
        if (t < 24) {
#pragma unroll
            for (int i = 0; i < 8; i++) cw[i] = nb[i];
        }
    }

    __syncthreads();

#pragma unroll
    for (int nt = 0; nt < 4; nt++)
#pragma unroll
        for (int r = 0; r < 4; r++)
            s_c4[(q * 4 + r) * 64 + nt * 16 + m] = acc4[nt][r];
    __syncthreads();

    {
        float bb = b4[tid];
        ushort4v res;
#pragma unroll
        for (int pp = 0; pp < 4; pp++) {
            int y0 = (pp >> 1) * 2, x0 = (pp & 1) * 2;
            float v0 = s_c4[(y0 * 4 + x0) * 64 + tid];
            float v1 = s_c4[(y0 * 4 + x0 + 1) * 64 + tid];
            float v2 = s_c4[((y0 + 1) * 4 + x0) * 64 + tid];
            float v3 = s_c4[((y0 + 1) * 4 + x0 + 1) * 64 + tid];
            res[pp] = f2bf(fmaxf(fmaxf(v0, v1), fmaxf(v2, v3)) + bb);
        }
        *(ushort4v*)(emb + (size_t)b * 256 + tid * 4) = res;
    }
}

// ---------------------------------------------------------------------------
// K5: fused heads (MFMA) + DAMP recurrence (verified R4-R6).
// ---------------------------------------------------------------------------
__global__ __launch_bounds__(256) void k_heads(
    const unsigned short* __restrict__ emb,
    const unsigned short* __restrict__ wph1,
    const float* __restrict__ cn_b1, const float* __restrict__ ep_b1,
    const unsigned short* __restrict__ wpcn2, const float* __restrict__ cn_b2,
    const unsigned short* __restrict__ wpep2, const float* __restrict__ ep_b2,
    float* __restrict__ out) {
    __shared__ unsigned short s_hid[16 * 520];
    __shared__ float s_conn[120 * 17];
    __shared__ float s_rec0[120 * 17];
    __shared__ float s_rec1[120 * 17];
    __shared__ float s_ep[36 * 17];
    const int tid = threadIdx.x;
    const int lane = tid & 63, wave = tid >> 6;
    const int m = lane & 15, q = lane >> 4;
    const int b0 = blockIdx.x * 16;

    float4v acc[8];
#pragma unroll
    for (int i = 0; i < 8; i++) acc[i] = (float4v){0.f, 0.f, 0.f, 0.f};
    const short8* wp1 = (const short8*)wph1;
    for (int kt = 0; kt < 8; kt++) {
        short8 av = *(const short8*)(emb + (size_t)(b0 + m) * 256 + kt * 32 + q * 8);
#pragma unroll
        for (int ntl = 0; ntl < 8; ntl++) {
            int nt = wave * 8 + ntl;
            short8 bv = wp1[(kt * 32 + nt) * 64 + lane];
            acc[ntl] = __builtin_amdgcn_mfma_f32_16x16x32_bf16(av, bv, acc[ntl], 0, 0, 0);
        }
    }
#pragma unroll
    for (int ntl = 0; ntl < 8; ntl++) {
        int c = (wave * 8 + ntl) * 16 + m;
        float bb = (c < 256) ? cn_b1[c] : ep_b1[c - 256];
#pragma unroll
        for (int r = 0; r < 4; r++)
            s_hid[(q * 4 + r) * 520 + c] = f2bf(fmaxf(acc[ntl][r] + bb, 0.f));
    }
    __syncthreads();

    for (int job = wave; job < 11; job += 4) {
        const bool isconn = job < 8;
        const int koff = isconn ? 0 : 256;
        float4v a2 = (float4v){0.f, 0.f, 0.f, 0.f};
        for (int kt = 0; kt < 8; kt++) {
            short8 av = *(const short8*)(s_hid + m * 520 + koff + kt * 32 + q * 8);
            short8 bv = isconn
                ? ((const short8*)wpcn2)[(kt * 8 + job) * 64 + lane]
                : ((const short8*)wpep2)[(kt * 3 + (job - 8)) * 64 + lane];
            a2 = __builtin_amdgcn_mfma_f32_16x16x32_bf16(av, bv, a2, 0, 0, 0);
        }
        int c = (isconn ? job : (job - 8)) * 16 + m;
        float bb = isconn ? (c < 120 ? cn_b2[c] : 0.f) : (c < 36 ? ep_b2[c] : 0.f);
#pragma unroll
        for (int r = 0; r < 4; r++) {
            float v = 1.f / (1.f + __expf(-(a2[r] + bb)));
            int row = q * 4 + r;
            if (isconn) {
                if (c < 120) { s_conn[c * 17 + row] = v; s_rec0[c * 17 + row] = v; }
            } else {
                if (c < 36) s_ep[c * 17 + row] = v;
            }
        }
    }
    __syncthreads();

    const int row = tid >> 4, g = tid & 15;
    const int ns = G16_START[g];
    const int nodecnt = G16_START[g + 1] - ns;
    int ie[3][4], icnt[3], os[3], oc[3];
    float cr[3][4];
#pragma unroll
    for (int s = 0; s < 3; s++) {
        if (s < nodecnt) {
            int n = ns + s;
            icnt[s] = ADJC.cnt[n];
#pragma unroll
            for (int qx = 0; qx < 4; qx++) ie[s][qx] = ADJC.idx[n][qx];
            os[s] = ADJC.ostart[n];
            oc[s] = ADJC.ocnt[n];
#pragma unroll
            for (int oe = 0; oe < 4; oe++)
                cr[s][oe] = (oe < oc[s]) ? s_conn[(os[s] + oe) * 17 + row] : 0.f;
        } else {
            icnt[s] = 0; oc[s] = 0; os[s] = 0;
#pragma unroll
            for (int qx = 0; qx < 4; qx++) ie[s][qx] = 0;
#pragma unroll
            for (int oe = 0; oe < 4; oe++) cr[s][oe] = 0.f;
        }
    }
    float old0 = (g == 0) ? s_conn[0 * 17 + row] : 0.f;

    for (int it = 0; it < 36; it++) {
        const float* cur = (it & 1) ? s_rec1 : s_rec0;
        float* nxt = (it & 1) ? s_rec0 : s_rec1;
#pragma unroll
        for (int s = 0; s < 3; s++) {
            float sum = 0.f;
#pragma unroll
            for (int qx = 0; qx < 4; qx++)
                sum += (qx < icnt[s]) ? cur[ie[s][qx] * 17 + row] : 0.f;
            sum = fminf(sum, 1.f);
#pragma unroll
            for (int oe = 0; oe < 4; oe++) {
                if (oe < oc[s]) {
                    int e = os[s] + oe;
                    float nv = sum * cr[s][oe];
                    nxt[e * 17 + row] = nv;
                    if (g == 0 && s == 0 && oe == 0)
                        old0 = fminf(old0 + nv, 1.f);
                }
            }
        }
        __syncthreads();
    }

    if (g == 0)
        out[b0 + row] = old0 * s_ep[0 * 17 + row] * s_ep[6 * 17 + row];
}

// ---------------------------------------------------------------------------
extern "C" void kernel_launch(void* const* d_in, const int* in_sizes, int n_in,
                              void* d_out, int out_size, void* d_ws, size_t ws_size,
                              hipStream_t stream) {
    const float* image = (const float*)d_in[0];
    const float* c1w = (const float*)d_in[1];
    const float* c1b = (const float*)d_in[2];
    const float* c2w = (const float*)d_in[3];
    const float* c2b = (const float*)d_in[4];
    const float* c3w = (const float*)d_in[5];
    const float* c3b = (const float*)d_in[6];
    const float* c4w = (const float*)d_in[7];
    const float* c4b = (const float*)d_in[8];
    const float* epw1 = (const float*)d_in[9];
    const float* epb1 = (const float*)d_in[10];
    const float* epw2 = (const float*)d_in[11];
    const float* epb2 = (const float*)d_in[12];
    const float* cnw1 = (const float*)d_in[13];
    const float* cnb1 = (const float*)d_in[14];
    const float* cnw2 = (const float*)d_in[15];
    const float* cnb2 = (const float*)d_in[16];

    const int B = in_sizes[0] / (32 * 32);  // 1024

    unsigned short* ws = (unsigned short*)d_ws;
    unsigned short* p2 = ws;                              // B*4608 bf16
    unsigned short* embo = p2 + (size_t)B * 4608;         // B*256 bf16
    unsigned short* wp2 = embo + (size_t)B * 256;         // 25600
    unsigned short* wp3 = wp2 + 25600;                    // 51200
    unsigned short* wp4 = wp3 + 51200;                    // 102400
    unsigned short* wph1 = wp4 + 102400;                  // 131072
    unsigned short* wpcn2 = wph1 + 131072;                // 32768
    unsigned short* wpep2 = wpcn2 + 32768;                // 12288

    k_prep<<<700, 256, 0, stream>>>(c2w, c3w, c4w, wp2, wp3, wp4);
    k_prep2<<<688, 256, 0, stream>>>(cnw1, epw1, cnw2, epw2, wph1, wpcn2, wpep2);
    k_conv12<<<B * 2, 128, 0, stream>>>(image, c1w, c1b, wp2, c2b, p2);
    k_conv34<<<B, 64, 0, stream>>>(p2, wp3, c3b, wp4, c4b, embo);
    k_heads<<<B / 16, 256, 0, stream>>>(embo, wph1, cnb1, epb1,
                                        wpcn2, cnb2, wpep2, epb2, (float*)d_out);
}

// Round 8
// 206.382 us; speedup vs baseline: 1.2396x; 1.2396x over previous
//
#include <hip/hip_runtime.h>
#include <math.h>

typedef __attribute__((ext_vector_type(8))) short short8;
typedef __attribute__((ext_vector_type(4))) float float4v;
typedef __attribute__((ext_vector_type(4))) unsigned short ushort4v;

static __device__ __forceinline__ unsigned short f2bf(float f) {
    union { float f; unsigned u; } v; v.f = f;
    unsigned u = v.u;
    return (unsigned short)((u + 0x7fffu + ((u >> 16) & 1u)) >> 16);
}
static __device__ __forceinline__ float bf2f(unsigned short h) {
    union { unsigned u; float f; } v; v.u = ((unsigned)h) << 16;
    return v.f;
}

// ---------------------------------------------------------------------------
// Graph structure (compile-time), matching Python enumeration order.
// ---------------------------------------------------------------------------
struct AdjT {
    int src[120];
    int dst[120];
    int cnt[36];
    int idx[36][4];    // incoming edges per node
    int ostart[36];    // outgoing edge run start
    int ocnt[36];      // outgoing edge run length
};

constexpr AdjT build_adj() {
    AdjT a{};
    const int ddx[4] = {-1, 0, 0, 1};
    const int ddy[4] = {0, -1, 1, 0};
    int ne = 0;
    for (int i = 0; i < 6; i++)
        for (int j = 0; j < 6; j++)
            for (int d = 0; d < 4; d++) {
                int x = i + ddx[d], y = j + ddy[d];
                if (x >= 0 && x < 6 && y >= 0 && y < 6) {
                    a.src[ne] = j * 6 + i;
                    a.dst[ne] = y * 6 + x;
                    ne++;
                }
            }
    for (int n = 0; n < 36; n++) {
        a.cnt[n] = 0;
        for (int e = 0; e < 120; e++)
            if (a.dst[e] == n) a.idx[n][a.cnt[n]++] = e;
    }
    for (int n = 0; n < 36; n++) { a.ostart[n] = 0; a.ocnt[n] = 0; }
    for (int e = 0; e < 120; e++) {
        a.ocnt[a.src[e]]++;
        if (e == 0 || a.src[e] != a.src[e - 1]) a.ostart[a.src[e]] = e;
    }
    return a;
}

__device__ constexpr AdjT ADJC = build_adj();
__device__ constexpr int G16_START[17] =
    {0, 3, 6, 9, 12, 14, 16, 18, 20, 22, 24, 26, 28, 30, 32, 34, 36};

// ---------------------------------------------------------------------------
// K0: weight prep — B-fragments (bf16) for conv1/conv2/conv3/conv4 MFMA.
//  wp1: [2 nt][64 lane][8 j]  co=nt*16+(lane&15), k=(lane>>4)*8+j (K=25 pad 32)
// grid 704*256 = 180224 = 25600 + 51200 + 102400 + 1024 exactly.
// ---------------------------------------------------------------------------
__global__ __launch_bounds__(256) void k_prep(const float* __restrict__ w1,
                                              const float* __restrict__ w2,
                                              const float* __restrict__ w3,
                                              const float* __restrict__ w4,
                                              unsigned short* __restrict__ wp1,
                                              unsigned short* __restrict__ wp2,
                                              unsigned short* __restrict__ wp3,
                                              unsigned short* __restrict__ wp4) {
    int e = blockIdx.x * 256 + threadIdx.x;
    if (e < 25600) {
        int j = e & 7, lane = (e >> 3) & 63, ct = (e >> 9) & 1, t = e >> 10;
        int co = ct * 16 + (lane & 15), ci = (lane >> 4) * 8 + j;
        wp2[e] = f2bf(w2[co * 800 + ci * 25 + t]);
    } else if (e < 76800) {
        int e3 = e - 25600;
        int j = e3 & 7, lane = (e3 >> 3) & 63, nt = (e3 >> 9) & 3, t = e3 >> 11;
        int co = nt * 16 + (lane & 15), ci = (lane >> 4) * 8 + j;
        wp3[e3] = f2bf(w3[(co * 32 + ci) * 25 + t]);
    } else if (e < 179200) {
        int e4 = e - 76800;
        int j = e4 & 7, lane = (e4 >> 3) & 63, nt = (e4 >> 9) & 3;
        int ks = (e4 >> 11) & 1, t = e4 >> 12;
        int co = nt * 16 + (lane & 15), ci = ks * 32 + (lane >> 4) * 8 + j;
        wp4[e4] = f2bf(w4[(co * 64 + ci) * 25 + t]);
    } else {
        int e1 = e - 179200;
        int j = e1 & 7, lane = (e1 >> 3) & 63, nt = (e1 >> 9) & 1;
        int n = lane & 15, q = lane >> 4;
        int k = q * 8 + j;
        wp1[e1] = (k < 25) ? f2bf(w1[(nt * 16 + n) * 25 + k]) : (unsigned short)0;
    }
}

// ---------------------------------------------------------------------------
// K0b: weight prep for heads MFMA (verified R4).
// ---------------------------------------------------------------------------
__global__ __launch_bounds__(256) void k_prep2(const float* __restrict__ cnw1,
                                               const float* __restrict__ epw1,
                                               const float* __restrict__ cnw2,
                                               const float* __restrict__ epw2,
                                               unsigned short* __restrict__ wph1,
                                               unsigned short* __restrict__ wpcn2,
                                               unsigned short* __restrict__ wpep2) {
    int e = blockIdx.x * 256 + threadIdx.x;
    if (e < 131072) {
        int j = e & 7, lane = (e >> 3) & 63, nt = (e >> 9) & 31, kt = e >> 14;
        int c = nt * 16 + (lane & 15);
        int k = kt * 32 + ((lane >> 4) << 3) + j;
        float v = (c < 256) ? cnw1[c * 256 + k] : epw1[(c - 256) * 256 + k];
        wph1[e] = f2bf(v);
    } else if (e < 163840) {
        int e2 = e - 131072;
        int j = e2 & 7, lane = (e2 >> 3) & 63, nt = (e2 >> 9) & 7, kt = e2 >> 12;
        int c = nt * 16 + (lane & 15);
        int k = kt * 32 + ((lane >> 4) << 3) + j;
        wpcn2[e2] = f2bf(c < 120 ? cnw2[c * 256 + k] : 0.f);
    } else {
        int e3 = e - 163840;
        int j = e3 & 7, lane = (e3 >> 3) & 63, idx = e3 >> 9;
        int kt = idx / 3, nt = idx - kt * 3;
        int c = nt * 16 + (lane & 15);
        int k = kt * 32 + ((lane >> 4) << 3) + j;
        wpep2[e3] = f2bf(c < 36 ? epw2[c * 256 + k] : 0.f);
    }
}

// ---------------------------------------------------------------------------
// K12: FUSED conv1 + conv2 + maxpool2.
// Block = half image (grid B*2), 128 threads (2 waves).
//  Phase A (conv1) — R8 rewrite as MFMA: K=25 GEMM (pad 32). Per wave 14
//    M-tiles x 2 N-tiles = 28 MFMAs (replaces 3200 VALU FMAs/thread — R7's
//    36 us VALU + 8-way-conflict b32 staging writes). A-frag = 8 ds_read_b32
//    gathers from s_img; acc initialized with bias; D staged straight into
//    s_buf in phase-B A-layout.
//  Phase B (conv2, MFMA): verified R5 tap-GEMM on s_buf; stage/pool epilogue
//    unioned onto s_buf; out = p2 ch-last bf16 [144][32].
// ---------------------------------------------------------------------------
__global__ __launch_bounds__(128) void k_conv12(const float* __restrict__ img,
                                                const float* __restrict__ b1,
                                                const unsigned short* __restrict__ wp1,
                                                const unsigned short* __restrict__ wprep,
                                                const float* __restrict__ bias2,
                                                unsigned short* __restrict__ out) {
    __shared__ float s_img[20 * 36];            // 20 rows x 32 cols, stride 36
    __shared__ unsigned short s_buf[448 * 40];  // conv1 out [448][40]; later stage [288][40]
    const int blk = blockIdx.x;
    const int b = blk >> 1, half = blk & 1;
    const int tid = threadIdx.x;
    const int lane = tid & 63, wave = tid >> 6;
    const int m = lane & 15, quad = lane >> 4;

    // stage image rows half*12 .. half*12+19 (640 floats = 160 float4)
    {
        const float4* g4 = (const float4*)(img + (size_t)b * 1024 + half * 12 * 32);
        for (int v = tid; v < 160; v += 128) {
            float4 t = g4[v];
            *(float4*)(s_img + (v >> 3) * 36 + (v & 7) * 4) = t;
        }
    }

    // B-frag prefetches (global, no LDS dependency)
    const short8* wp = (const short8*)wprep;
    short8 bw0 = wp[lane];
    short8 bw1 = wp[64 + lane];
    short8 w1b0 = ((const short8*)wp1)[lane];
    short8 w1b1 = ((const short8*)wp1)[64 + lane];
    const float bb0 = b1[m], bb1 = b1[16 + m];

    // per-lane tap offsets & valid masks for conv1 A-frag (k = quad*8+j)
    int toff[8];
    unsigned short vm[8];
#pragma unroll
    for (int j = 0; j < 8; j++) {
        int k = quad * 8 + j;
        int kk = (k < 25) ? k : 0;
        int ky = kk / 5, kx = kk - ky * 5;
        toff[j] = ky * 36 + kx;
        vm[j] = (k < 25) ? (unsigned short)0xFFFFu : (unsigned short)0;
    }

    __syncthreads();

    // ---- phase A: conv1 via MFMA ----
    for (int mt = wave * 14; mt < (wave + 1) * 14; mt++) {
        int pos = mt * 16 + m;
        int y = pos / 28, x = pos - y * 28;
        const float* wb = s_img + y * 36 + x;
        short8 av;
#pragma unroll
        for (int j = 0; j < 8; j++)
            av[j] = (short)(f2bf(wb[toff[j]]) & vm[j]);
        float4v a0 = {bb0, bb0, bb0, bb0};
        float4v a1 = {bb1, bb1, bb1, bb1};
        a0 = __builtin_amdgcn_mfma_f32_16x16x32_bf16(av, w1b0, a0, 0, 0, 0);
        a1 = __builtin_amdgcn_mfma_f32_16x16x32_bf16(av, w1b1, a1, 0, 0, 0);
        int pb = mt * 16 + quad * 4;
#pragma unroll
        for (int r = 0; r < 4; r++) {
            s_buf[(pb + r) * 40 + m] = f2bf(a0[r]);
            s_buf[(pb + r) * 40 + 16 + m] = f2bf(a1[r]);
        }
    }
    __syncthreads();

    // ---- phase B: conv2 tap-GEMM (verified R5 structure) ----
    int a_idx[9];
#pragma unroll
    for (int mt = 0; mt < 9; mt++) {
        int p = wave * 144 + mt * 16 + m;
        int yl = p / 24;
        int x = p - yl * 24;
        a_idx[mt] = (yl * 28 + x) * 40 + quad * 8;
    }

    float4v acc[9][2];
#pragma unroll
    for (int mt = 0; mt < 9; mt++) {
        acc[mt][0] = (float4v){0.f, 0.f, 0.f, 0.f};
        acc[mt][1] = (float4v){0.f, 0.f, 0.f, 0.f};
    }

    for (int t = 0; t < 25; t++) {
        short8 nb0, nb1;
        if (t < 24) {
            nb0 = wp[(t + 1) * 128 + lane];
            nb1 = wp[(t + 1) * 128 + 64 + lane];
        }
        const int ky = t / 5, kx = t - ky * 5;
        const int toff2 = (ky * 28 + kx) * 40;
#pragma unroll
        for (int mt = 0; mt < 9; mt++) {
            short8 av = *(const short8*)(s_buf + a_idx[mt] + toff2);
            acc[mt][0] = __builtin_amdgcn_mfma_f32_16x16x32_bf16(av, bw0, acc[mt][0], 0, 0, 0);
            acc[mt][1] = __builtin_amdgcn_mfma_f32_16x16x32_bf16(av, bw1, acc[mt][1], 0, 0, 0);
        }
        if (t < 24) { bw0 = nb0; bw1 = nb1; }
    }

    __syncthreads();  // all A-reads done before stage overwrites s_buf

    const int n = lane & 15;
#pragma unroll
    for (int mt = 0; mt < 9; mt++) {
        int pbase = wave * 144 + mt * 16 + quad * 4;
#pragma unroll
        for (int r = 0; r < 4; r++) {
            s_buf[(pbase + r) * 40 + n] = f2bf(acc[mt][0][r]);
            s_buf[(pbase + r) * 40 + 16 + n] = f2bf(acc[mt][1][r]);
        }
    }
    __syncthreads();

    unsigned short* op = out + (size_t)b * 4608;
    for (int i = tid; i < 2304; i += 128) {
        int co = i & 31;
        int pos = i >> 5;
        int prl = pos / 12;
        int px = pos - prl * 12;
        int base = ((prl * 2) * 24 + px * 2) * 40 + co;
        float v0 = bf2f(s_buf[base]);
        float v1 = bf2f(s_buf[base + 40]);
        float v2 = bf2f(s_buf[base + 24 * 40]);
        float v3 = bf2f(s_buf[base + 25 * 40]);
        float mx = fmaxf(fmaxf(v0, v1), fmaxf(v2, v3));
        op[((half * 6 + prl) * 12 + px) * 32 + co] = f2bf(mx + bias2[co]);
    }
}

// ---------------------------------------------------------------------------
// K34: fused conv3 + conv4 + pool + flatten via MFMA tap-GEMM (verified R3-R7).
// ---------------------------------------------------------------------------
__global__ __launch_bounds__(64) void k_conv34(const unsigned short* __restrict__ p2,
                                               const unsigned short* __restrict__ wp3,
                                               const float* __restrict__ b3,
                                               const unsigned short* __restrict__ wp4,
                                               const float* __restrict__ b4,
                                               unsigned short* __restrict__ emb) {
    __shared__ unsigned short s_buf34[9216];  // s_in [0,4608) | s_c3 [4608,9216)
    unsigned short* s_in = s_buf34;
    unsigned short* s_c3 = s_buf34 + 4608;    // [64][72] padded
    float* s_c4 = (float*)s_buf34;            // [16][64] — reuses s_in region
    const int b = blockIdx.x, tid = threadIdx.x;
    const int m = tid & 15, q = tid >> 4;

    {
        const short8* g8 = (const short8*)(p2 + (size_t)b * 4608);
        short8* s8 = (short8*)s_in;
        for (int i = tid; i < 576; i += 64) s8[i] = g8[i];
    }

    int a_base[4];
#pragma unroll
    for (int mt = 0; mt < 4; mt++) {
        int p = mt * 16 + m;
        int y = p >> 3, x = p & 7;
        a_base[mt] = (y * 12 + x) * 32 + q * 8;
    }

    float4v acc3[4][4];
#pragma unroll
    for (int mt = 0; mt < 4; mt++)
#pragma unroll
        for (int nt = 0; nt < 4; nt++) acc3[mt][nt] = (float4v){0.f, 0.f, 0.f, 0.f};

    const short8* wp = (const short8*)wp3;
    short8 bw[4];
#pragma unroll
    for (int nt = 0; nt < 4; nt++) bw[nt] = wp[nt * 64 + tid];

    __syncthreads();

    for (int t = 0; t < 25; t++) {
        short8 nb[4];
        if (t < 24) {
#pragma unroll
            for (int nt = 0; nt < 4; nt++) nb[nt] = wp[((t + 1) * 4 + nt) * 64 + tid];
        }
        const int ky = t / 5, kx = t - ky * 5;
        const int toff = (ky * 12 + kx) * 32;
#pragma unroll
        for (int mt = 0; mt < 4; mt++) {
            short8 av = *(const short8*)(s_in + a_base[mt] + toff);
#pragma unroll
            for (int nt = 0; nt < 4; nt++)
                acc3[mt][nt] = __builtin_amdgcn_mfma_f32_16x16x32_bf16(av, bw[nt], acc3[mt][nt], 0, 0, 0);
        }
        if (t < 24) {
#pragma unroll
            for (int nt = 0; nt < 4; nt++) bw[nt] = nb[nt];
        }
    }

    {
        float bb[4];
#pragma unroll
        for (int nt = 0; nt < 4; nt++) bb[nt] = b3[nt * 16 + m];
#pragma unroll
        for (int mt = 0; mt < 4; mt++)
#pragma unroll
            for (int nt = 0; nt < 4; nt++)
#pragma unroll
                for (int r = 0; r < 4; r++)
                    s_c3[(mt * 16 + q * 4 + r) * 72 + nt * 16 + m] =
                        f2bf(acc3[mt][nt][r] + bb[nt]);
    }
    __syncthreads();

    const int a4_base = ((m >> 2) * 8 + (m & 3)) * 72 + q * 8;
    float4v acc4[4];
#pragma unroll
    for (int nt = 0; nt < 4; nt++) acc4[nt] = (float4v){0.f, 0.f, 0.f, 0.f};

    const short8* wq = (const short8*)wp4;
    short8 cw[8];
#pragma unroll
    for (int i = 0; i < 8; i++) cw[i] = wq[i * 64 + tid];

    for (int t = 0; t < 25; t++) {
        short8 nb[8];
        if (t < 24) {
#pragma unroll
            for (int i = 0; i < 8; i++) nb[i] = wq[((t + 1) * 8 + i) * 64 + tid];
        }
        const int ky = t / 5, kx = t - ky * 5;
        const int toff = (ky * 8 + kx) * 72;
#pragma unroll
        for (int ks = 0; ks < 2; ks++) {
            short8 av = *(const short8*)(s_c3 + a4_base + toff + ks * 32);
#pragma unroll
            for (int nt = 0; nt < 4; nt++)
                acc4[nt] = __builtin_amdgcn_mfma_f32_16x16x32_bf16(av, cw[ks * 4 + nt], acc4[nt], 0, 0, 0);
        }
        if (t < 24) {
#pragma unroll
            for (int i = 0; i < 8; i++) cw[i] = nb[i];
        }
    }

    __syncthreads();

#pragma unroll
    for (int nt = 0; nt < 4; nt++)
#pragma unroll
        for (int r = 0; r < 4; r++)
            s_c4[(q * 4 + r) * 64 + nt * 16 + m] = acc4[nt][r];
    __syncthreads();

    {
        float bb = b4[tid];
        ushort4v res;
#pragma unroll
        for (int pp = 0; pp < 4; pp++) {
            int y0 = (pp >> 1) * 2, x0 = (pp & 1) * 2;
            float v0 = s_c4[(y0 * 4 + x0) * 64 + tid];
            float v1 = s_c4[(y0 * 4 + x0 + 1) * 64 + tid];
            float v2 = s_c4[((y0 + 1) * 4 + x0) * 64 + tid];
            float v3 = s_c4[((y0 + 1) * 4 + x0 + 1) * 64 + tid];
            res[pp] = f2bf(fmaxf(fmaxf(v0, v1), fmaxf(v2, v3)) + bb);
        }
        *(ushort4v*)(emb + (size_t)b * 256 + tid * 4) = res;
    }
}

// ---------------------------------------------------------------------------
// K5: fused heads (MFMA) + DAMP recurrence (verified R4-R7).
// ---------------------------------------------------------------------------
__global__ __launch_bounds__(256) void k_heads(
    const unsigned short* __restrict__ emb,
    const unsigned short* __restrict__ wph1,
    const float* __restrict__ cn_b1, const float* __restrict__ ep_b1,
    const unsigned short* __restrict__ wpcn2, const float* __restrict__ cn_b2,
    const unsigned short* __restrict__ wpep2, const float* __restrict__ ep_b2,
    float* __restrict__ out) {
    __shared__ unsigned short s_hid[16 * 520];
    __shared__ float s_conn[120 * 17];
    __shared__ float s_rec0[120 * 17];
    __shared__ float s_rec1[120 * 17];
    __shared__ float s_ep[36 * 17];
    const int tid = threadIdx.x;
    const int lane = tid & 63, wave = tid >> 6;
    const int m = lane & 15, q = lane >> 4;
    const int b0 = blockIdx.x * 16;

    float4v acc[8];
#pragma unroll
    for (int i = 0; i < 8; i++) acc[i] = (float4v){0.f, 0.f, 0.f, 0.f};
    const short8* wp1 = (const short8*)wph1;
    for (int kt = 0; kt < 8; kt++) {
        short8 av = *(const short8*)(emb + (size_t)(b0 + m) * 256 + kt * 32 + q * 8);
#pragma unroll
        for (int ntl = 0; ntl < 8; ntl++) {
            int nt = wave * 8 + ntl;
            short8 bv = wp1[(kt * 32 + nt) * 64 + lane];
            acc[ntl] = __builtin_amdgcn_mfma_f32_16x16x32_bf16(av, bv, acc[ntl], 0, 0, 0);
        }
    }
#pragma unroll
    for (int ntl = 0; ntl < 8; ntl++) {
        int c = (wave * 8 + ntl) * 16 + m;
        float bb = (c < 256) ? cn_b1[c] : ep_b1[c - 256];
#pragma unroll
        for (int r = 0; r < 4; r++)
            s_hid[(q * 4 + r) * 520 + c] = f2bf(fmaxf(acc[ntl][r] + bb, 0.f));
    }
    __syncthreads();

    for (int job = wave; job < 11; job += 4) {
        const bool isconn = job < 8;
        const int koff = isconn ? 0 : 256;
        float4v a2 = (float4v){0.f, 0.f, 0.f, 0.f};
        for (int kt = 0; kt < 8; kt++) {
            short8 av = *(const short8*)(s_hid + m * 520 + koff + kt * 32 + q * 8);
            short8 bv = isconn
                ? ((const short8*)wpcn2)[(kt * 8 + job) * 64 + lane]
                : ((const short8*)wpep2)[(kt * 3 + (job - 8)) * 64 + lane];
            a2 = __builtin_amdgcn_mfma_f32_16x16x32_bf16(av, bv, a2, 0, 0, 0);
        }
        int c = (isconn ? job : (job - 8)) * 16 + m;
        float bb = isconn ? (c < 120 ? cn_b2[c] : 0.f) : (c < 36 ? ep_b2[c] : 0.f);
#pragma unroll
        for (int r = 0; r < 4; r++) {
            float v = 1.f / (1.f + __expf(-(a2[r] + bb)));
            int row = q * 4 + r;
            if (isconn) {
                if (c < 120) { s_conn[c * 17 + row] = v; s_rec0[c * 17 + row] = v; }
            } else {
                if (c < 36) s_ep[c * 17 + row] = v;
            }
        }
    }
    __syncthreads();

    const int row = tid >> 4, g = tid & 15;
    const int ns = G16_START[g];
    const int nodecnt = G16_START[g + 1] - ns;
    int ie[3][4], icnt[3], os[3], oc[3];
    float cr[3][4];
#pragma unroll
    for (int s = 0; s < 3; s++) {
        if (s < nodecnt) {
            int n = ns + s;
            icnt[s] = ADJC.cnt[n];
#pragma unroll
            for (int qx = 0; qx < 4; qx++) ie[s][qx] = ADJC.idx[n][qx];
            os[s] = ADJC.ostart[n];
            oc[s] = ADJC.ocnt[n];
#pragma unroll
            for (int oe = 0; oe < 4; oe++)
                cr[s][oe] = (oe < oc[s]) ? s_conn[(os[s] + oe) * 17 + row] : 0.f;
        } else {
            icnt[s] = 0; oc[s] = 0; os[s] = 0;
#pragma unroll
            for (int qx = 0; qx < 4; qx++) ie[s][qx] = 0;
#pragma unroll
            for (int oe = 0; oe < 4; oe++) cr[s][oe] = 0.f;
        }
    }
    float old0 = (g == 0) ? s_conn[0 * 17 + row] : 0.f;

    for (int it = 0; it < 36; it++) {
        const float* cur = (it & 1) ? s_rec1 : s_rec0;
        float* nxt = (it & 1) ? s_rec0 : s_rec1;
#pragma unroll
        for (int s = 0; s < 3; s++) {
            float sum = 0.f;
#pragma unroll
            for (int qx = 0; qx < 4; qx++)
                sum += (qx < icnt[s]) ? cur[ie[s][qx] * 17 + row] : 0.f;
            sum = fminf(sum, 1.f);
#pragma unroll
            for (int oe = 0; oe < 4; oe++) {
                if (oe < oc[s]) {
                    int e = os[s] + oe;
                    float nv = sum * cr[s][oe];
                    nxt[e * 17 + row] = nv;
                    if (g == 0 && s == 0 && oe == 0)
                        old0 = fminf(old0 + nv, 1.f);
                }
            }
        }
        __syncthreads();
    }

    if (g == 0)
        out[b0 + row] = old0 * s_ep[0 * 17 + row] * s_ep[6 * 17 + row];
}

// ---------------------------------------------------------------------------
extern "C" void kernel_launch(void* const* d_in, const int* in_sizes, int n_in,
                              void* d_out, int out_size, void* d_ws, size_t ws_size,
                              hipStream_t stream) {
    const float* image = (const float*)d_in[0];
    const float* c1w = (const float*)d_in[1];
    const float* c1b = (const float*)d_in[2];
    const float* c2w = (const float*)d_in[3];
    const float* c2b = (const float*)d_in[4];
    const float* c3w = (const float*)d_in[5];
    const float* c3b = (const float*)d_in[6];
    const float* c4w = (const float*)d_in[7];
    const float* c4b = (const float*)d_in[8];
    const float* epw1 = (const float*)d_in[9];
    const float* epb1 = (const float*)d_in[10];
    const float* epw2 = (const float*)d_in[11];
    const float* epb2 = (const float*)d_in[12];
    const float* cnw1 = (const float*)d_in[13];
    const float* cnb1 = (const float*)d_in[14];
    const float* cnw2 = (const float*)d_in[15];
    const float* cnb2 = (const float*)d_in[16];

    const int B = in_sizes[0] / (32 * 32);  // 1024

    unsigned short* ws = (unsigned short*)d_ws;
    unsigned short* p2 = ws;                              // B*4608 bf16
    unsigned short* embo = p2 + (size_t)B * 4608;         // B*256 bf16
    unsigned short* wp2 = embo + (size_t)B * 256;         // 25600
    unsigned short* wp3 = wp2 + 25600;                    // 51200
    unsigned short* wp4 = wp3 + 51200;                    // 102400
    unsigned short* wph1 = wp4 + 102400;                  // 131072
    unsigned short* wpcn2 = wph1 + 131072;                // 32768
    unsigned short* wpep2 = wpcn2 + 32768;                // 12288
    unsigned short* wp1 = wpep2 + 12288;                  // 1024

    k_prep<<<704, 256, 0, stream>>>(c1w, c2w, c3w, c4w, wp1, wp2, wp3, wp4);
    k_prep2<<<688, 256, 0, stream>>>(cnw1, epw1, cnw2, epw2, wph1, wpcn2, wpep2);
    k_conv12<<<B * 2, 128, 0, stream>>>(image, c1b, wp1, wp2, c2b, p2);
    k_conv34<<<B, 64, 0, stream>>>(p2, wp3, c3b, wp4, c4b, embo);
    k_heads<<<B / 16, 256, 0, stream>>>(embo, wph1, cnb1, epb1,
                                        wpcn2, cnb2, wpep2, epb2, (float*)d_out);
}

// Round 9
// 176.497 us; speedup vs baseline: 1.4495x; 1.1693x over previous
//
#include <hip/hip_runtime.h>
#include <math.h>

typedef __attribute__((ext_vector_type(8))) short short8;
typedef __attribute__((ext_vector_type(4))) float float4v;
typedef __attribute__((ext_vector_type(4))) unsigned short ushort4v;

static __device__ __forceinline__ unsigned short f2bf(float f) {
    union { float f; unsigned u; } v; v.f = f;
    unsigned u = v.u;
    return (unsigned short)((u + 0x7fffu + ((u >> 16) & 1u)) >> 16);
}
static __device__ __forceinline__ float bf2f(unsigned short h) {
    union { unsigned u; float f; } v; v.u = ((unsigned)h) << 16;
    return v.f;
}
static __device__ __forceinline__ unsigned pk2(float a, float b) {
    return (unsigned)f2bf(a) | ((unsigned)f2bf(b) << 16);
}

// ---------------------------------------------------------------------------
// Graph structure (compile-time), matching Python enumeration order.
// ---------------------------------------------------------------------------
struct AdjT {
    int src[120];
    int dst[120];
    int cnt[36];
    int idx[36][4];
    int ostart[36];
    int ocnt[36];
};

constexpr AdjT build_adj() {
    AdjT a{};
    const int ddx[4] = {-1, 0, 0, 1};
    const int ddy[4] = {0, -1, 1, 0};
    int ne = 0;
    for (int i = 0; i < 6; i++)
        for (int j = 0; j < 6; j++)
            for (int d = 0; d < 4; d++) {
                int x = i + ddx[d], y = j + ddy[d];
                if (x >= 0 && x < 6 && y >= 0 && y < 6) {
                    a.src[ne] = j * 6 + i;
                    a.dst[ne] = y * 6 + x;
                    ne++;
                }
            }
    for (int n = 0; n < 36; n++) {
        a.cnt[n] = 0;
        for (int e = 0; e < 120; e++)
            if (a.dst[e] == n) a.idx[n][a.cnt[n]++] = e;
    }
    for (int n = 0; n < 36; n++) { a.ostart[n] = 0; a.ocnt[n] = 0; }
    for (int e = 0; e < 120; e++) {
        a.ocnt[a.src[e]]++;
        if (e == 0 || a.src[e] != a.src[e - 1]) a.ostart[a.src[e]] = e;
    }
    return a;
}

__device__ constexpr AdjT ADJC = build_adj();
__device__ constexpr int G16_START[17] =
    {0, 3, 6, 9, 12, 14, 16, 18, 20, 22, 24, 26, 28, 30, 32, 34, 36};

// ---------------------------------------------------------------------------
// K0: merged weight prep. Conv B-frags use COLUMN-INTERLEAVED tiles:
// tile nt holds cols co = W*n + nt  (W=2 for conv1/conv2, W=4 for conv3/4),
// so one lane's per-tile outputs are ADJACENT channels -> packed staging
// writes in natural [pos][ch] LDS layout (kills the transpose scatter).
// Layout (flat):
//  wp1 [2 nt][64][8]          co=2n+nt,  k=q*8+j (K=25 pad 32, zeros)
//  wp2 [25 t][2 ct][64][8]    co=2n+ct,  ci=q*8+j
//  wp3 [25 t][4 nt][64][8]    co=4n+nt,  ci=q*8+j
//  wp4 [25 t][2 ks][4 nt][64][8] co=4n+nt, ci=ks*32+q*8+j
// Heads preps unchanged (natural cols).
// grid 1392*256 = 356352 = 180224 (conv) + 176128 (heads) exactly.
// ---------------------------------------------------------------------------
__global__ __launch_bounds__(256) void k_prepall(
    const float* __restrict__ w1, const float* __restrict__ w2,
    const float* __restrict__ w3, const float* __restrict__ w4,
    const float* __restrict__ cnw1, const float* __restrict__ epw1,
    const float* __restrict__ cnw2, const float* __restrict__ epw2,
    unsigned short* __restrict__ wp1, unsigned short* __restrict__ wp2,
    unsigned short* __restrict__ wp3, unsigned short* __restrict__ wp4,
    unsigned short* __restrict__ wph1, unsigned short* __restrict__ wpcn2,
    unsigned short* __restrict__ wpep2) {
    int e = blockIdx.x * 256 + threadIdx.x;
    if (e < 180224) {
        if (e < 25600) {
            int j = e & 7, lane = (e >> 3) & 63, ct = (e >> 9) & 1, t = e >> 10;
            int co = 2 * (lane & 15) + ct, ci = (lane >> 4) * 8 + j;
            wp2[e] = f2bf(w2[co * 800 + ci * 25 + t]);
        } else if (e < 76800) {
            int e3 = e - 25600;
            int j = e3 & 7, lane = (e3 >> 3) & 63, nt = (e3 >> 9) & 3, t = e3 >> 11;
            int co = 4 * (lane & 15) + nt, ci = (lane >> 4) * 8 + j;
            wp3[e3] = f2bf(w3[(co * 32 + ci) * 25 + t]);
        } else if (e < 179200) {
            int e4 = e - 76800;
            int j = e4 & 7, lane = (e4 >> 3) & 63, nt = (e4 >> 9) & 3;
            int ks = (e4 >> 11) & 1, t = e4 >> 12;
            int co = 4 * (lane & 15) + nt, ci = ks * 32 + (lane >> 4) * 8 + j;
            wp4[e4] = f2bf(w4[(co * 64 + ci) * 25 + t]);
        } else {
            int e1 = e - 179200;
            int j = e1 & 7, lane = (e1 >> 3) & 63, nt = (e1 >> 9) & 1;
            int n = lane & 15, q = lane >> 4;
            int k = q * 8 + j;
            int co = 2 * n + nt;
            wp1[e1] = (k < 25) ? f2bf(w1[co * 25 + k]) : (unsigned short)0;
        }
    } else {
        int eh = e - 180224;
        if (eh < 131072) {
            int j = eh & 7, lane = (eh >> 3) & 63, nt = (eh >> 9) & 31, kt = eh >> 14;
            int c = nt * 16 + (lane & 15);
            int k = kt * 32 + ((lane >> 4) << 3) + j;
            float v = (c < 256) ? cnw1[c * 256 + k] : epw1[(c - 256) * 256 + k];
            wph1[eh] = f2bf(v);
        } else if (eh < 163840) {
            int e2 = eh - 131072;
            int j = e2 & 7, lane = (e2 >> 3) & 63, nt = (e2 >> 9) & 7, kt = e2 >> 12;
            int c = nt * 16 + (lane & 15);
            int k = kt * 32 + ((lane >> 4) << 3) + j;
            wpcn2[e2] = f2bf(c < 120 ? cnw2[c * 256 + k] : 0.f);
        } else {
            int e3 = eh - 163840;
            int j = e3 & 7, lane = (e3 >> 3) & 63, idx = e3 >> 9;
            int kt = idx / 3, nt = idx - kt * 3;
            int c = nt * 16 + (lane & 15);
            int k = kt * 32 + ((lane >> 4) << 3) + j;
            wpep2[e3] = f2bf(c < 36 ? epw2[c * 256 + k] : 0.f);
        }
    }
}

// ---------------------------------------------------------------------------
// K_CONVALL: the whole CNN (conv1..conv4 + pools + flatten) in one kernel.
// Block = 1 image, 256 threads (4 waves). All intermediates in one LDS
// union (s_buf, 62.7 KB, stride-40/72 rows for bank spread):
//   conv1 out [784][40]            (whole buffer)
//   conv2 stage [576][40]          [0 .. 23040)      (conv1 dead)
//   p2 (pooled, +bias) [144][40]   [23040 .. 28800)  (conv1 tail dead)
//   s_c3 [64][72]                  [0 .. 4608)       (stage dead)
//   s_c4 f32 [16][68]              byte 16384..20736 (disjoint from s_c3/p2)
// Phases (verified structures from R5-R8, re-distributed over 4 waves):
//   conv1: 49 Mtiles strided by wave, K=25-pad-32 MFMA, packed b32 staging.
//   conv2: 36 Mtiles strided by wave, 25-tap GEMM, packed b32 staging.
//   pool2+bias -> p2; conv3: Mtile=wave, 4 interleaved Ntiles, b64 staging.
//   conv4: Ntile=wave, 2 Ksteps; emb = pool+bias+flatten (tid = co*4+pp).
// ---------------------------------------------------------------------------
__global__ __launch_bounds__(256) void k_convall(
    const float* __restrict__ img, const float* __restrict__ b1,
    const unsigned short* __restrict__ wp1,
    const unsigned short* __restrict__ wp2, const float* __restrict__ b2,
    const unsigned short* __restrict__ wp3, const float* __restrict__ b3,
    const unsigned short* __restrict__ wp4, const float* __restrict__ b4,
    unsigned short* __restrict__ emb) {
    __shared__ float s_img[32 * 36];
    __shared__ unsigned short s_buf[784 * 40];
    const int b = blockIdx.x, tid = threadIdx.x;
    const int lane = tid & 63, wave = tid >> 6;
    const int m = lane & 15, quad = lane >> 4;
    const int P2O = 23040;

    // stage full image: 256 threads x 1 float4 = 1024 floats
    {
        float4 t = ((const float4*)(img + (size_t)b * 1024))[tid];
        *(float4*)(s_img + (tid >> 3) * 36 + (tid & 7) * 4) = t;
    }

    // conv1 B-frags + per-lane tap gather offsets (K=25 pad 32)
    short8 w1b0 = ((const short8*)wp1)[lane];
    short8 w1b1 = ((const short8*)wp1)[64 + lane];
    const float c1b0 = b1[2 * m], c1b1 = b1[2 * m + 1];
    int toff1[8];
    unsigned short vm1[8];
#pragma unroll
    for (int j = 0; j < 8; j++) {
        int k = quad * 8 + j;
        int kk = (k < 25) ? k : 0;
        int ky = kk / 5, kx = kk - ky * 5;
        toff1[j] = ky * 36 + kx;
        vm1[j] = (k < 25) ? (unsigned short)0xFFFFu : (unsigned short)0;
    }
    // conv2 B-frag prefetch
    const short8* wq2 = (const short8*)wp2;
    short8 bw0 = wq2[lane];
    short8 bw1 = wq2[64 + lane];

    __syncthreads();

    // ---- conv1 via MFMA: pos = mt*16+m over 784; packed b32 staging ----
    for (int mt = wave; mt < 49; mt += 4) {
        int pos = mt * 16 + m;
        int y = pos / 28, x = pos - y * 28;
        const float* wb = s_img + y * 36 + x;
        short8 av;
#pragma unroll
        for (int j = 0; j < 8; j++)
            av[j] = (short)(f2bf(wb[toff1[j]]) & vm1[j]);
        float4v a0 = {c1b0, c1b0, c1b0, c1b0};
        float4v a1 = {c1b1, c1b1, c1b1, c1b1};
        a0 = __builtin_amdgcn_mfma_f32_16x16x32_bf16(av, w1b0, a0, 0, 0, 0);
        a1 = __builtin_amdgcn_mfma_f32_16x16x32_bf16(av, w1b1, a1, 0, 0, 0);
        int pb = mt * 16 + quad * 4;
#pragma unroll
        for (int r = 0; r < 4; r++)
            *(unsigned*)(s_buf + (pb + r) * 40 + 2 * m) = pk2(a0[r], a1[r]);
    }
    __syncthreads();

    // ---- conv2 tap-GEMM: 9 Mtiles/wave ----
    int a_idx[9];
#pragma unroll
    for (int i9 = 0; i9 < 9; i9++) {
        int p = (i9 * 4 + wave) * 16 + m;  // pos2 in 24x24 grid
        int y2 = p / 24, x2 = p - y2 * 24;
        a_idx[i9] = (y2 * 28 + x2) * 40 + quad * 8;
    }
    float4v acc[9][2];
#pragma unroll
    for (int i9 = 0; i9 < 9; i9++) {
        acc[i9][0] = (float4v){0.f, 0.f, 0.f, 0.f};
        acc[i9][1] = (float4v){0.f, 0.f, 0.f, 0.f};
    }
    for (int t = 0; t < 25; t++) {
        short8 nb0, nb1;
        if (t < 24) {
            nb0 = wq2[(t + 1) * 128 + lane];
            nb1 = wq2[(t + 1) * 128 + 64 + lane];
        }
        const int ky = t / 5, kx = t - ky * 5;
        const int toff = (ky * 28 + kx) * 40;
#pragma unroll
        for (int i9 = 0; i9 < 9; i9++) {
            short8 av = *(const short8*)(s_buf + a_idx[i9] + toff);
            acc[i9][0] = __builtin_amdgcn_mfma_f32_16x16x32_bf16(av, bw0, acc[i9][0], 0, 0, 0);
            acc[i9][1] = __builtin_amdgcn_mfma_f32_16x16x32_bf16(av, bw1, acc[i9][1], 0, 0, 0);
        }
        if (t < 24) { bw0 = nb0; bw1 = nb1; }
    }
    __syncthreads();  // all conv2 A-reads done before stage overwrites

    // stage conv2 out: packed b32, natural [pos2][co] layout
#pragma unroll
    for (int i9 = 0; i9 < 9; i9++) {
        int pb = (i9 * 4 + wave) * 16 + quad * 4;
#pragma unroll
        for (int r = 0; r < 4; r++)
            *(unsigned*)(s_buf + (pb + r) * 40 + 2 * m) = pk2(acc[i9][0][r], acc[i9][1][r]);
    }
    __syncthreads();

    // pool 2x2 + bias2 -> p2 [144][40] at P2O
    for (int i = tid; i < 4608; i += 256) {
        int co = i & 31, pos12 = i >> 5;
        int prl = pos12 / 12, px = pos12 - prl * 12;
        int base = ((prl * 2) * 24 + px * 2) * 40 + co;
        float v0 = bf2f(s_buf[base]);
        float v1 = bf2f(s_buf[base + 40]);
        float v2 = bf2f(s_buf[base + 960]);
        float v3 = bf2f(s_buf[base + 1000]);
        float mx = fmaxf(fmaxf(v0, v1), fmaxf(v2, v3));
        s_buf[P2O + pos12 * 40 + co] = f2bf(mx + b2[co]);
    }
    __syncthreads();

    // ---- conv3: Mtile = wave (pos3 = wave*16+m in 8x8 grid), 4 Ntiles ----
    {
        int pos3 = wave * 16 + m;
        int y3 = pos3 >> 3, x3 = pos3 & 7;
        int a3 = P2O + (y3 * 12 + x3) * 40 + quad * 8;
        float4v acc3[4];
#pragma unroll
        for (int nt = 0; nt < 4; nt++) acc3[nt] = (float4v){0.f, 0.f, 0.f, 0.f};
        const short8* wq3 = (const short8*)wp3;
        short8 bw3[4];
#pragma unroll
        for (int nt = 0; nt < 4; nt++) bw3[nt] = wq3[nt * 64 + lane];
        for (int t = 0; t < 25; t++) {
            short8 nb3[4];
            if (t < 24) {
#pragma unroll
                for (int nt = 0; nt < 4; nt++)
                    nb3[nt] = wq3[((t + 1) * 4 + nt) * 64 + lane];
            }
            const int ky = t / 5, kx = t - ky * 5;
            short8 av = *(const short8*)(s_buf + a3 + (ky * 12 + kx) * 40);
#pragma unroll
            for (int nt = 0; nt < 4; nt++)
                acc3[nt] = __builtin_amdgcn_mfma_f32_16x16x32_bf16(av, bw3[nt], acc3[nt], 0, 0, 0);
            if (t < 24) {
#pragma unroll
                for (int nt = 0; nt < 4; nt++) bw3[nt] = nb3[nt];
            }
        }
        // stage s_c3 [64][72] (+bias3): packed b64, natural [pos3][co]
#pragma unroll
        for (int r = 0; r < 4; r++) {
            int row3 = wave * 16 + quad * 4 + r;
            ushort4v pk;
#pragma unroll
            for (int nt = 0; nt < 4; nt++)
                pk[nt] = f2bf(acc3[nt][r] + b3[4 * m + nt]);
            *(ushort4v*)(s_buf + row3 * 72 + 4 * m) = pk;
        }
    }
    __syncthreads();

    // ---- conv4: Ntile = wave (cols co = 4n+wave), 2 Ksteps ----
    {
        int y4 = m >> 2, x4 = m & 3;
        int a4 = (y4 * 8 + x4) * 72 + quad * 8;
        float4v acc4 = (float4v){0.f, 0.f, 0.f, 0.f};
        const short8* wq4 = (const short8*)wp4;
        short8 cw0 = wq4[(0 * 4 + wave) * 64 + lane];
        short8 cw1 = wq4[(1 * 4 + wave) * 64 + lane];
        for (int t = 0; t < 25; t++) {
            short8 n0, n1;
            if (t < 24) {
                n0 = wq4[(((t + 1) * 2) * 4 + wave) * 64 + lane];
                n1 = wq4[(((t + 1) * 2 + 1) * 4 + wave) * 64 + lane];
            }
            const int ky = t / 5, kx = t - ky * 5;
            const int toff = (ky * 8 + kx) * 72;
            short8 av0 = *(const short8*)(s_buf + a4 + toff);
            acc4 = __builtin_amdgcn_mfma_f32_16x16x32_bf16(av0, cw0, acc4, 0, 0, 0);
            short8 av1 = *(const short8*)(s_buf + a4 + toff + 32);
            acc4 = __builtin_amdgcn_mfma_f32_16x16x32_bf16(av1, cw1, acc4, 0, 0, 0);
            if (t < 24) { cw0 = n0; cw1 = n1; }
        }
        // s_c4 f32 [16][68] at byte 16384 (disjoint from s_c3 [0..9216))
        float* s_c4 = (float*)(s_buf + 8192);
#pragma unroll
        for (int r = 0; r < 4; r++)
            s_c4[(quad * 4 + r) * 68 + 4 * m + wave] = acc4[r];
    }
    __syncthreads();

    // emb epilogue: tid = co*4 + pp; pool 2x2 + bias4 + flatten
    {
        const float* s_c4 = (const float*)(s_buf + 8192);
        int co = tid >> 2, pp = tid & 3;
        int ppy = pp >> 1, ppx = pp & 1;
        float v0 = s_c4[((2 * ppy) * 4 + 2 * ppx) * 68 + co];
        float v1 = s_c4[((2 * ppy) * 4 + 2 * ppx + 1) * 68 + co];
        float v2 = s_c4[((2 * ppy + 1) * 4 + 2 * ppx) * 68 + co];
        float v3 = s_c4[((2 * ppy + 1) * 4 + 2 * ppx + 1) * 68 + co];
        emb[(size_t)b * 256 + tid] =
            f2bf(fmaxf(fmaxf(v0, v1), fmaxf(v2, v3)) + b4[co]);
    }
}

// ---------------------------------------------------------------------------
// K5: fused heads (MFMA) + DAMP recurrence (verified R4-R8, unchanged).
// ---------------------------------------------------------------------------
__global__ __launch_bounds__(256) void k_heads(
    const unsigned short* __restrict__ emb,
    const unsigned short* __restrict__ wph1,
    const float* __restrict__ cn_b1, const float* __restrict__ ep_b1,
    const unsigned short* __restrict__ wpcn2, const float* __restrict__ cn_b2,
    const unsigned short* __restrict__ wpep2, const float* __restrict__ ep_b2,
    float* __restrict__ out) {
    __shared__ unsigned short s_hid[16 * 520];
    __shared__ float s_conn[120 * 17];
    __shared__ float s_rec0[120 * 17];
    __shared__ float s_rec1[120 * 17];
    __shared__ float s_ep[36 * 17];
    const int tid = threadIdx.x;
    const int lane = tid & 63, wave = tid >> 6;
    const int m = lane & 15, q = lane >> 4;
    const int b0 = blockIdx.x * 16;

    float4v acc[8];
#pragma unroll
    for (int i = 0; i < 8; i++) acc[i] = (float4v){0.f, 0.f, 0.f, 0.f};
    const short8* wp1 = (const short8*)wph1;
    for (int kt = 0; kt < 8; kt++) {
        short8 av = *(const short8*)(emb + (size_t)(b0 + m) * 256 + kt * 32 + q * 8);
#pragma unroll
        for (int ntl = 0; ntl < 8; ntl++) {
            int nt = wave * 8 + ntl;
            short8 bv = wp1[(kt * 32 + nt) * 64 + lane];
            acc[ntl] = __builtin_amdgcn_mfma_f32_16x16x32_bf16(av, bv, acc[ntl], 0, 0, 0);
        }
    }
#pragma unroll
    for (int ntl = 0; ntl < 8; ntl++) {
        int c = (wave * 8 + ntl) * 16 + m;
        float bb = (c < 256) ? cn_b1[c] : ep_b1[c - 256];
#pragma unroll
        for (int r = 0; r < 4; r++)
            s_hid[(q * 4 + r) * 520 + c] = f2bf(fmaxf(acc[ntl][r] + bb, 0.f));
    }
    __syncthreads();

    for (int job = wave; job < 11; job += 4) {
        const bool isconn = job < 8;
        const int koff = isconn ? 0 : 256;
        float4v a2 = (float4v){0.f, 0.f, 0.f, 0.f};
        for (int kt = 0; kt < 8; kt++) {
            short8 av = *(const short8*)(s_hid + m * 520 + koff + kt * 32 + q * 8);
            short8 bv = isconn
                ? ((const short8*)wpcn2)[(kt * 8 + job) * 64 + lane]
                : ((const short8*)wpep2)[(kt * 3 + (job - 8)) * 64 + lane];
            a2 = __builtin_amdgcn_mfma_f32_16x16x32_bf16(av, bv, a2, 0, 0, 0);
        }
        int c = (isconn ? job : (job - 8)) * 16 + m;
        float bb = isconn ? (c < 120 ? cn_b2[c] : 0.f) : (c < 36 ? ep_b2[c] : 0.f);
#pragma unroll
        for (int r = 0; r < 4; r++) {
            float v = 1.f / (1.f + __expf(-(a2[r] + bb)));
            int row = q * 4 + r;
            if (isconn) {
                if (c < 120) { s_conn[c * 17 + row] = v; s_rec0[c * 17 + row] = v; }
            } else {
                if (c < 36) s_ep[c * 17 + row] = v;
            }
        }
    }
    __syncthreads();

    const int row = tid >> 4, g = tid & 15;
    const int ns = G16_START[g];
    const int nodecnt = G16_START[g + 1] - ns;
    int ie[3][4], icnt[3], os[3], oc[3];
    float cr[3][4];
#pragma unroll
    for (int s = 0; s < 3; s++) {
        if (s < nodecnt) {
            int n = ns + s;
            icnt[s] = ADJC.cnt[n];
#pragma unroll
            for (int qx = 0; qx < 4; qx++) ie[s][qx] = ADJC.idx[n][qx];
            os[s] = ADJC.ostart[n];
            oc[s] = ADJC.ocnt[n];
#pragma unroll
            for (int oe = 0; oe < 4; oe++)
                cr[s][oe] = (oe < oc[s]) ? s_conn[(os[s] + oe) * 17 + row] : 0.f;
        } else {
            icnt[s] = 0; oc[s] = 0; os[s] = 0;
#pragma unroll
            for (int qx = 0; qx < 4; qx++) ie[s][qx] = 0;
#pragma unroll
            for (int oe = 0; oe < 4; oe++) cr[s][oe] = 0.f;
        }
    }
    float old0 = (g == 0) ? s_conn[0 * 17 + row] : 0.f;

    for (int it = 0; it < 36; it++) {
        const float* cur = (it & 1) ? s_rec1 : s_rec0;
        float* nxt = (it & 1) ? s_rec0 : s_rec1;
#pragma unroll
        for (int s = 0; s < 3; s++) {
            float sum = 0.f;
#pragma unroll
            for (int qx = 0; qx < 4; qx++)
                sum += (qx < icnt[s]) ? cur[ie[s][qx] * 17 + row] : 0.f;
            sum = fminf(sum, 1.f);
#pragma unroll
            for (int oe = 0; oe < 4; oe++) {
                if (oe < oc[s]) {
                    int e = os[s] + oe;
                    float nv = sum * cr[s][oe];
                    nxt[e * 17 + row] = nv;
                    if (g == 0 && s == 0 && oe == 0)
                        old0 = fminf(old0 + nv, 1.f);
                }
            }
        }
        __syncthreads();
    }

    if (g == 0)
        out[b0 + row] = old0 * s_ep[0 * 17 + row] * s_ep[6 * 17 + row];
}

// ---------------------------------------------------------------------------
extern "C" void kernel_launch(void* const* d_in, const int* in_sizes, int n_in,
                              void* d_out, int out_size, void* d_ws, size_t ws_size,
                              hipStream_t stream) {
    const float* image = (const float*)d_in[0];
    const float* c1w = (const float*)d_in[1];
    const float* c1b = (const float*)d_in[2];
    const float* c2w = (const float*)d_in[3];
    const float* c2b = (const float*)d_in[4];
    const float* c3w = (const float*)d_in[5];
    const float* c3b = (const float*)d_in[6];
    const float* c4w = (const float*)d_in[7];
    const float* c4b = (const float*)d_in[8];
    const float* epw1 = (const float*)d_in[9];
    const float* epb1 = (const float*)d_in[10];
    const float* epw2 = (const float*)d_in[11];
    const float* epb2 = (const float*)d_in[12];
    const float* cnw1 = (const float*)d_in[13];
    const float* cnb1 = (const float*)d_in[14];
    const float* cnw2 = (const float*)d_in[15];
    const float* cnb2 = (const float*)d_in[16];

    const int B = in_sizes[0] / (32 * 32);  // 1024

    unsigned short* ws = (unsigned short*)d_ws;
    unsigned short* embo = ws;                            // B*256 bf16
    unsigned short* wp2 = embo + (size_t)B * 256;         // 25600
    unsigned short* wp3 = wp2 + 25600;                    // 51200
    unsigned short* wp4 = wp3 + 51200;                    // 102400
    unsigned short* wph1 = wp4 + 102400;                  // 131072
    unsigned short* wpcn2 = wph1 + 131072;                // 32768
    unsigned short* wpep2 = wpcn2 + 32768;                // 12288
    unsigned short* wp1 = wpep2 + 12288;                  // 1024

    k_prepall<<<1392, 256, 0, stream>>>(c1w, c2w, c3w, c4w, cnw1, epw1, cnw2, epw2,
                                        wp1, wp2, wp3, wp4, wph1, wpcn2, wpep2);
    k_convall<<<B, 256, 0, stream>>>(image, c1b, wp1, wp2, c2b, wp3, c3b, wp4, c4b, embo);
    k_heads<<<B / 16, 256, 0, stream>>>(embo, wph1, cnb1, epb1,
                                        wpcn2, cnb2, wpep2, epb2, (float*)d_out);
}

// Round 10
// 173.272 us; speedup vs baseline: 1.4764x; 1.0186x over previous
//
#include <hip/hip_runtime.h>
#include <math.h>

typedef __attribute__((ext_vector_type(8))) short short8;
typedef __attribute__((ext_vector_type(4))) float float4v;
typedef __attribute__((ext_vector_type(4))) unsigned short ushort4v;

static __device__ __forceinline__ unsigned short f2bf(float f) {
    union { float f; unsigned u; } v; v.f = f;
    unsigned u = v.u;
    return (unsigned short)((u + 0x7fffu + ((u >> 16) & 1u)) >> 16);
}
static __device__ __forceinline__ float bf2f(unsigned short h) {
    union { unsigned u; float f; } v; v.u = ((unsigned)h) << 16;
    return v.f;
}
static __device__ __forceinline__ unsigned pk2(float a, float b) {
    return (unsigned)f2bf(a) | ((unsigned)f2bf(b) << 16);
}

// ---------------------------------------------------------------------------
// Graph structure (compile-time), matching Python enumeration order.
// ---------------------------------------------------------------------------
struct AdjT {
    int src[120];
    int dst[120];
    int cnt[36];
    int idx[36][4];
    int ostart[36];
    int ocnt[36];
};

constexpr AdjT build_adj() {
    AdjT a{};
    const int ddx[4] = {-1, 0, 0, 1};
    const int ddy[4] = {0, -1, 1, 0};
    int ne = 0;
    for (int i = 0; i < 6; i++)
        for (int j = 0; j < 6; j++)
            for (int d = 0; d < 4; d++) {
                int x = i + ddx[d], y = j + ddy[d];
                if (x >= 0 && x < 6 && y >= 0 && y < 6) {
                    a.src[ne] = j * 6 + i;
                    a.dst[ne] = y * 6 + x;
                    ne++;
                }
            }
    for (int n = 0; n < 36; n++) {
        a.cnt[n] = 0;
        for (int e = 0; e < 120; e++)
            if (a.dst[e] == n) a.idx[n][a.cnt[n]++] = e;
    }
    for (int n = 0; n < 36; n++) { a.ostart[n] = 0; a.ocnt[n] = 0; }
    for (int e = 0; e < 120; e++) {
        a.ocnt[a.src[e]]++;
        if (e == 0 || a.src[e] != a.src[e - 1]) a.ostart[a.src[e]] = e;
    }
    return a;
}

__device__ constexpr AdjT ADJC = build_adj();
__device__ constexpr int G16_START[17] =
    {0, 3, 6, 9, 12, 14, 16, 18, 20, 22, 24, 26, 28, 30, 32, 34, 36};

// ---------------------------------------------------------------------------
// K0: merged weight prep (verified R9). Column-interleaved conv B-frags.
// ---------------------------------------------------------------------------
__global__ __launch_bounds__(256) void k_prepall(
    const float* __restrict__ w1, const float* __restrict__ w2,
    const float* __restrict__ w3, const float* __restrict__ w4,
    const float* __restrict__ cnw1, const float* __restrict__ epw1,
    const float* __restrict__ cnw2, const float* __restrict__ epw2,
    unsigned short* __restrict__ wp1, unsigned short* __restrict__ wp2,
    unsigned short* __restrict__ wp3, unsigned short* __restrict__ wp4,
    unsigned short* __restrict__ wph1, unsigned short* __restrict__ wpcn2,
    unsigned short* __restrict__ wpep2) {
    int e = blockIdx.x * 256 + threadIdx.x;
    if (e < 180224) {
        if (e < 25600) {
            int j = e & 7, lane = (e >> 3) & 63, ct = (e >> 9) & 1, t = e >> 10;
            int co = 2 * (lane & 15) + ct, ci = (lane >> 4) * 8 + j;
            wp2[e] = f2bf(w2[co * 800 + ci * 25 + t]);
        } else if (e < 76800) {
            int e3 = e - 25600;
            int j = e3 & 7, lane = (e3 >> 3) & 63, nt = (e3 >> 9) & 3, t = e3 >> 11;
            int co = 4 * (lane & 15) + nt, ci = (lane >> 4) * 8 + j;
            wp3[e3] = f2bf(w3[(co * 32 + ci) * 25 + t]);
        } else if (e < 179200) {
            int e4 = e - 76800;
            int j = e4 & 7, lane = (e4 >> 3) & 63, nt = (e4 >> 9) & 3;
            int ks = (e4 >> 11) & 1, t = e4 >> 12;
            int co = 4 * (lane & 15) + nt, ci = ks * 32 + (lane >> 4) * 8 + j;
            wp4[e4] = f2bf(w4[(co * 64 + ci) * 25 + t]);
        } else {
            int e1 = e - 179200;
            int j = e1 & 7, lane = (e1 >> 3) & 63, nt = (e1 >> 9) & 1;
            int n = lane & 15, q = lane >> 4;
            int k = q * 8 + j;
            int co = 2 * n + nt;
            wp1[e1] = (k < 25) ? f2bf(w1[co * 25 + k]) : (unsigned short)0;
        }
    } else {
        int eh = e - 180224;
        if (eh < 131072) {
            int j = eh & 7, lane = (eh >> 3) & 63, nt = (eh >> 9) & 31, kt = eh >> 14;
            int c = nt * 16 + (lane & 15);
            int k = kt * 32 + ((lane >> 4) << 3) + j;
            float v = (c < 256) ? cnw1[c * 256 + k] : epw1[(c - 256) * 256 + k];
            wph1[eh] = f2bf(v);
        } else if (eh < 163840) {
            int e2 = eh - 131072;
            int j = e2 & 7, lane = (e2 >> 3) & 63, nt = (e2 >> 9) & 7, kt = e2 >> 12;
            int c = nt * 16 + (lane & 15);
            int k = kt * 32 + ((lane >> 4) << 3) + j;
            wpcn2[e2] = f2bf(c < 120 ? cnw2[c * 256 + k] : 0.f);
        } else {
            int e3 = eh - 163840;
            int j = e3 & 7, lane = (e3 >> 3) & 63, idx = e3 >> 9;
            int kt = idx / 3, nt = idx - kt * 3;
            int c = nt * 16 + (lane & 15);
            int k = kt * 32 + ((lane >> 4) << 3) + j;
            wpep2[e3] = f2bf(c < 36 ? epw2[c * 256 + k] : 0.f);
        }
    }
}

// ---------------------------------------------------------------------------
// K_CONVALL: whole CNN in one kernel. R10: 512 threads (8 waves) per image
// (same 67.5 KB LDS -> still 2 blocks/CU but 4 waves/SIMD, 2x latency hiding).
// Phase work redistributed: conv1 mt stride 8; conv2 5/4 Mtiles per wave;
// conv3 tile=wave>>1 with Ntile halves by wave parity; conv4 waves 0-3.
// ---------------------------------------------------------------------------
__global__ __launch_bounds__(512) void k_convall(
    const float* __restrict__ img, const float* __restrict__ b1,
    const unsigned short* __restrict__ wp1,
    const unsigned short* __restrict__ wp2, const float* __restrict__ b2,
    const unsigned short* __restrict__ wp3, const float* __restrict__ b3,
    const unsigned short* __restrict__ wp4, const float* __restrict__ b4,
    unsigned short* __restrict__ emb) {
    __shared__ float s_img[32 * 36];
    __shared__ unsigned short s_buf[784 * 40];
    const int b = blockIdx.x, tid = threadIdx.x;
    const int lane = tid & 63, wave = tid >> 6;
    const int m = lane & 15, quad = lane >> 4;
    const int P2O = 23040;

    // stage full image (first 256 threads, float4 each)
    if (tid < 256) {
        float4 t = ((const float4*)(img + (size_t)b * 1024))[tid];
        *(float4*)(s_img + (tid >> 3) * 36 + (tid & 7) * 4) = t;
    }

    // conv1 B-frags + per-lane tap gather offsets (K=25 pad 32)
    short8 w1b0 = ((const short8*)wp1)[lane];
    short8 w1b1 = ((const short8*)wp1)[64 + lane];
    const float c1b0 = b1[2 * m], c1b1 = b1[2 * m + 1];
    int toff1[8];
    unsigned short vm1[8];
#pragma unroll
    for (int j = 0; j < 8; j++) {
        int k = quad * 8 + j;
        int kk = (k < 25) ? k : 0;
        int ky = kk / 5, kx = kk - ky * 5;
        toff1[j] = ky * 36 + kx;
        vm1[j] = (k < 25) ? (unsigned short)0xFFFFu : (unsigned short)0;
    }
    // conv2 B-frag prefetch
    const short8* wq2 = (const short8*)wp2;
    short8 bw0 = wq2[lane];
    short8 bw1 = wq2[64 + lane];

    __syncthreads();

    // ---- conv1 via MFMA: 49 Mtiles, stride 8 over waves ----
    for (int mt = wave; mt < 49; mt += 8) {
        int pos = mt * 16 + m;
        int y = pos / 28, x = pos - y * 28;
        const float* wb = s_img + y * 36 + x;
        short8 av;
#pragma unroll
        for (int j = 0; j < 8; j++)
            av[j] = (short)(f2bf(wb[toff1[j]]) & vm1[j]);
        float4v a0 = {c1b0, c1b0, c1b0, c1b0};
        float4v a1 = {c1b1, c1b1, c1b1, c1b1};
        a0 = __builtin_amdgcn_mfma_f32_16x16x32_bf16(av, w1b0, a0, 0, 0, 0);
        a1 = __builtin_amdgcn_mfma_f32_16x16x32_bf16(av, w1b1, a1, 0, 0, 0);
        int pb = mt * 16 + quad * 4;
#pragma unroll
        for (int r = 0; r < 4; r++)
            *(unsigned*)(s_buf + (pb + r) * 40 + 2 * m) = pk2(a0[r], a1[r]);
    }
    __syncthreads();

    // ---- conv2 tap-GEMM: 36 Mtiles -> waves 0-3: 5, waves 4-7: 4 ----
    const int nm2 = (wave < 4) ? 5 : 4;
    int a_idx[5];
#pragma unroll
    for (int i9 = 0; i9 < 5; i9++) {
        int M = i9 * 8 + wave;
        if (M > 35) M = 35;  // clamped dummy (unused when i9>=nm2)
        int p = M * 16 + m;
        int y2 = p / 24, x2 = p - y2 * 24;
        a_idx[i9] = (y2 * 28 + x2) * 40 + quad * 8;
    }
    float4v acc[5][2];
#pragma unroll
    for (int i9 = 0; i9 < 5; i9++) {
        acc[i9][0] = (float4v){0.f, 0.f, 0.f, 0.f};
        acc[i9][1] = (float4v){0.f, 0.f, 0.f, 0.f};
    }
    for (int t = 0; t < 25; t++) {
        short8 nb0, nb1;
        if (t < 24) {
            nb0 = wq2[(t + 1) * 128 + lane];
            nb1 = wq2[(t + 1) * 128 + 64 + lane];
        }
        const int ky = t / 5, kx = t - ky * 5;
        const int toff = (ky * 28 + kx) * 40;
#pragma unroll
        for (int i9 = 0; i9 < 5; i9++) {
            if (i9 < nm2) {
                short8 av = *(const short8*)(s_buf + a_idx[i9] + toff);
                acc[i9][0] = __builtin_amdgcn_mfma_f32_16x16x32_bf16(av, bw0, acc[i9][0], 0, 0, 0);
                acc[i9][1] = __builtin_amdgcn_mfma_f32_16x16x32_bf16(av, bw1, acc[i9][1], 0, 0, 0);
            }
        }
        if (t < 24) { bw0 = nb0; bw1 = nb1; }
    }
    __syncthreads();  // all conv2 A-reads done before stage overwrites

    // stage conv2 out: packed b32, natural [pos2][co] layout
#pragma unroll
    for (int i9 = 0; i9 < 5; i9++) {
        if (i9 < nm2) {
            int pb = (i9 * 8 + wave) * 16 + quad * 4;
#pragma unroll
            for (int r = 0; r < 4; r++)
                *(unsigned*)(s_buf + (pb + r) * 40 + 2 * m) = pk2(acc[i9][0][r], acc[i9][1][r]);
        }
    }
    __syncthreads();

    // pool 2x2 + bias2 -> p2 [144][40] at P2O
    for (int i = tid; i < 4608; i += 512) {
        int co = i & 31, pos12 = i >> 5;
        int prl = pos12 / 12, px = pos12 - prl * 12;
        int base = ((prl * 2) * 24 + px * 2) * 40 + co;
        float v0 = bf2f(s_buf[base]);
        float v1 = bf2f(s_buf[base + 40]);
        float v2 = bf2f(s_buf[base + 960]);
        float v3 = bf2f(s_buf[base + 1000]);
        float mx = fmaxf(fmaxf(v0, v1), fmaxf(v2, v3));
        s_buf[P2O + pos12 * 40 + co] = f2bf(mx + b2[co]);
    }
    __syncthreads();

    // ---- conv3: Mtile = wave>>1 (pos3 in 8x8 grid), Ntile half = wave&1 ----
    {
        int pos3 = (wave >> 1) * 16 + m;
        int y3 = pos3 >> 3, x3 = pos3 & 7;
        int a3 = P2O + (y3 * 12 + x3) * 40 + quad * 8;
        int nt0 = (wave & 1) * 2;
        float4v acc3[2];
        acc3[0] = (float4v){0.f, 0.f, 0.f, 0.f};
        acc3[1] = (float4v){0.f, 0.f, 0.f, 0.f};
        const short8* wq3 = (const short8*)wp3;
        short8 bw3[2];
        bw3[0] = wq3[nt0 * 64 + lane];
        bw3[1] = wq3[(nt0 + 1) * 64 + lane];
        for (int t = 0; t < 25; t++) {
            short8 nb3[2];
            if (t < 24) {
                nb3[0] = wq3[((t + 1) * 4 + nt0) * 64 + lane];
                nb3[1] = wq3[((t + 1) * 4 + nt0 + 1) * 64 + lane];
            }
            const int ky = t / 5, kx = t - ky * 5;
            short8 av = *(const short8*)(s_buf + a3 + (ky * 12 + kx) * 40);
            acc3[0] = __builtin_amdgcn_mfma_f32_16x16x32_bf16(av, bw3[0], acc3[0], 0, 0, 0);
            acc3[1] = __builtin_amdgcn_mfma_f32_16x16x32_bf16(av, bw3[1], acc3[1], 0, 0, 0);
            if (t < 24) { bw3[0] = nb3[0]; bw3[1] = nb3[1]; }
        }
        __syncthreads();  // p2 reads done before s_c3 overwrites s_buf[0..)
        // stage s_c3 [64][72] (+bias3): packed b32 (2 adjacent co)
        float bb0 = b3[4 * m + nt0], bb1 = b3[4 * m + nt0 + 1];
#pragma unroll
        for (int r = 0; r < 4; r++) {
            int row3 = (wave >> 1) * 16 + quad * 4 + r;
            *(unsigned*)(s_buf + row3 * 72 + 4 * m + nt0) =
                pk2(acc3[0][r] + bb0, acc3[1][r] + bb1);
        }
    }
    __syncthreads();

    // ---- conv4: waves 0-3 (Ntile = wave, 2 Ksteps); waves 4-7 idle ----
    if (wave < 4) {
        int y4 = m >> 2, x4 = m & 3;
        int a4 = (y4 * 8 + x4) * 72 + quad * 8;
        float4v acc4 = (float4v){0.f, 0.f, 0.f, 0.f};
        const short8* wq4 = (const short8*)wp4;
        short8 cw0 = wq4[(0 * 4 + wave) * 64 + lane];
        short8 cw1 = wq4[(1 * 4 + wave) * 64 + lane];
        for (int t = 0; t < 25; t++) {
            short8 n0, n1;
            if (t < 24) {
                n0 = wq4[(((t + 1) * 2) * 4 + wave) * 64 + lane];
                n1 = wq4[(((t + 1) * 2 + 1) * 4 + wave) * 64 + lane];
            }
            const int ky = t / 5, kx = t - ky * 5;
            const int toff = (ky * 8 + kx) * 72;
            short8 av0 = *(const short8*)(s_buf + a4 + toff);
            acc4 = __builtin_amdgcn_mfma_f32_16x16x32_bf16(av0, cw0, acc4, 0, 0, 0);
            short8 av1 = *(const short8*)(s_buf + a4 + toff + 32);
            acc4 = __builtin_amdgcn_mfma_f32_16x16x32_bf16(av1, cw1, acc4, 0, 0, 0);
            if (t < 24) { cw0 = n0; cw1 = n1; }
        }
        __syncthreads();  // s_c3 reads done before s_c4 overlays
        float* s_c4 = (float*)(s_buf + 8192);
#pragma unroll
        for (int r = 0; r < 4; r++)
            s_c4[(quad * 4 + r) * 68 + 4 * m + wave] = acc4[r];
    } else {
        __syncthreads();  // match conv4 waves' barrier
    }
    __syncthreads();

    // emb epilogue: tid = co*4 + pp; pool 2x2 + bias4 + flatten
    if (tid < 256) {
        const float* s_c4 = (const float*)(s_buf + 8192);
        int co = tid >> 2, pp = tid & 3;
        int ppy = pp >> 1, ppx = pp & 1;
        float v0 = s_c4[((2 * ppy) * 4 + 2 * ppx) * 68 + co];
        float v1 = s_c4[((2 * ppy) * 4 + 2 * ppx + 1) * 68 + co];
        float v2 = s_c4[((2 * ppy + 1) * 4 + 2 * ppx) * 68 + co];
        float v3 = s_c4[((2 * ppy + 1) * 4 + 2 * ppx + 1) * 68 + co];
        emb[(size_t)b * 256 + tid] =
            f2bf(fmaxf(fmaxf(v0, v1), fmaxf(v2, v3)) + b4[co]);
    }
}

// ---------------------------------------------------------------------------
// K5: fused heads (MFMA) + DAMP recurrence. R10: phase-3 barriers replaced by
// wave-local sync — row = tid>>4 puts each row's 16 groups in ONE wave, so
// rec producer/consumer always share a wave; s_waitcnt lgkmcnt(0) + compiler
// fence is sufficient (no cross-wave LDS traffic in the loop).
// ---------------------------------------------------------------------------
__global__ __launch_bounds__(256) void k_heads(
    const unsigned short* __restrict__ emb,
    const unsigned short* __restrict__ wph1,
    const float* __restrict__ cn_b1, const float* __restrict__ ep_b1,
    const unsigned short* __restrict__ wpcn2, const float* __restrict__ cn_b2,
    const unsigned short* __restrict__ wpep2, const float* __restrict__ ep_b2,
    float* __restrict__ out) {
    __shared__ unsigned short s_hid[16 * 520];
    __shared__ float s_conn[120 * 17];
    __shared__ float s_rec0[120 * 17];
    __shared__ float s_rec1[120 * 17];
    __shared__ float s_ep[36 * 17];
    const int tid = threadIdx.x;
    const int lane = tid & 63, wave = tid >> 6;
    const int m = lane & 15, q = lane >> 4;
    const int b0 = blockIdx.x * 16;

    float4v acc[8];
#pragma unroll
    for (int i = 0; i < 8; i++) acc[i] = (float4v){0.f, 0.f, 0.f, 0.f};
    const short8* wp1 = (const short8*)wph1;
    for (int kt = 0; kt < 8; kt++) {
        short8 av = *(const short8*)(emb + (size_t)(b0 + m) * 256 + kt * 32 + q * 8);
#pragma unroll
        for (int ntl = 0; ntl < 8; ntl++) {
            int nt = wave * 8 + ntl;
            short8 bv = wp1[(kt * 32 + nt) * 64 + lane];
            acc[ntl] = __builtin_amdgcn_mfma_f32_16x16x32_bf16(av, bv, acc[ntl], 0, 0, 0);
        }
    }
#pragma unroll
    for (int ntl = 0; ntl < 8; ntl++) {
        int c = (wave * 8 + ntl) * 16 + m;
        float bb = (c < 256) ? cn_b1[c] : ep_b1[c - 256];
#pragma unroll
        for (int r = 0; r < 4; r++)
            s_hid[(q * 4 + r) * 520 + c] = f2bf(fmaxf(acc[ntl][r] + bb, 0.f));
    }
    __syncthreads();

    for (int job = wave; job < 11; job += 4) {
        const bool isconn = job < 8;
        const int koff = isconn ? 0 : 256;
        float4v a2 = (float4v){0.f, 0.f, 0.f, 0.f};
        for (int kt = 0; kt < 8; kt++) {
            short8 av = *(const short8*)(s_hid + m * 520 + koff + kt * 32 + q * 8);
            short8 bv = isconn
                ? ((const short8*)wpcn2)[(kt * 8 + job) * 64 + lane]
                : ((const short8*)wpep2)[(kt * 3 + (job - 8)) * 64 + lane];
            a2 = __builtin_amdgcn_mfma_f32_16x16x32_bf16(av, bv, a2, 0, 0, 0);
        }
        int c = (isconn ? job : (job - 8)) * 16 + m;
        float bb = isconn ? (c < 120 ? cn_b2[c] : 0.f) : (c < 36 ? ep_b2[c] : 0.f);
#pragma unroll
        for (int r = 0; r < 4; r++) {
            float v = 1.f / (1.f + __expf(-(a2[r] + bb)));
            int row = q * 4 + r;
            if (isconn) {
                if (c < 120) { s_conn[c * 17 + row] = v; s_rec0[c * 17 + row] = v; }
            } else {
                if (c < 36) s_ep[c * 17 + row] = v;
            }
        }
    }
    __syncthreads();

    const int row = tid >> 4, g = tid & 15;
    const int ns = G16_START[g];
    const int nodecnt = G16_START[g + 1] - ns;
    int ie[3][4], icnt[3], os[3], oc[3];
    float cr[3][4];
#pragma unroll
    for (int s = 0; s < 3; s++) {
        if (s < nodecnt) {
            int n = ns + s;
            icnt[s] = ADJC.cnt[n];
#pragma unroll
            for (int qx = 0; qx < 4; qx++) ie[s][qx] = ADJC.idx[n][qx];
            os[s] = ADJC.ostart[n];
            oc[s] = ADJC.ocnt[n];
#pragma unroll
            for (int oe = 0; oe < 4; oe++)
                cr[s][oe] = (oe < oc[s]) ? s_conn[(os[s] + oe) * 17 + row] : 0.f;
        } else {
            icnt[s] = 0; oc[s] = 0; os[s] = 0;
#pragma unroll
            for (int qx = 0; qx < 4; qx++) ie[s][qx] = 0;
#pragma unroll
            for (int oe = 0; oe < 4; oe++) cr[s][oe] = 0.f;
        }
    }
    float old0 = (g == 0) ? s_conn[0 * 17 + row] : 0.f;

    for (int it = 0; it < 36; it++) {
        const float* cur = (it & 1) ? s_rec1 : s_rec0;
        float* nxt = (it & 1) ? s_rec0 : s_rec1;
#pragma unroll
        for (int s = 0; s < 3; s++) {
            float sum = 0.f;
#pragma unroll
            for (int qx = 0; qx < 4; qx++)
                sum += (qx < icnt[s]) ? cur[ie[s][qx] * 17 + row] : 0.f;
            sum = fminf(sum, 1.f);
#pragma unroll
            for (int oe = 0; oe < 4; oe++) {
                if (oe < oc[s]) {
                    int e = os[s] + oe;
                    float nv = sum * cr[s][oe];
                    nxt[e * 17 + row] = nv;
                    if (g == 0 && s == 0 && oe == 0)
                        old0 = fminf(old0 + nv, 1.f);
                }
            }
        }
        // wave-local sync: all comm is intra-wave (same row => same wave).
        __asm__ volatile("s_waitcnt lgkmcnt(0)" ::: "memory");
    }

    if (g == 0)
        out[b0 + row] = old0 * s_ep[0 * 17 + row] * s_ep[6 * 17 + row];
}

// ---------------------------------------------------------------------------
extern "C" void kernel_launch(void* const* d_in, const int* in_sizes, int n_in,
                              void* d_out, int out_size, void* d_ws, size_t ws_size,
                              hipStream_t stream) {
    const float* image = (const float*)d_in[0];
    const float* c1w = (const float*)d_in[1];
    const float* c1b = (const float*)d_in[2];
    const float* c2w = (const float*)d_in[3];
    const float* c2b = (const float*)d_in[4];
    const float* c3w = (const float*)d_in[5];
    const float* c3b = (const float*)d_in[6];
    const float* c4w = (const float*)d_in[7];
    const float* c4b = (const float*)d_in[8];
    const float* epw1 = (const float*)d_in[9];
    const float* epb1 = (const float*)d_in[10];
    const float* epw2 = (const float*)d_in[11];
    const float* epb2 = (const float*)d_in[12];
    const float* cnw1 = (const float*)d_in[13];
    const float* cnb1 = (const float*)d_in[14];
    const float* cnw2 = (const float*)d_in[15];
    const float* cnb2 = (const float*)d_in[16];

    const int B = in_sizes[0] / (32 * 32);  // 1024

    unsigned short* ws = (unsigned short*)d_ws;
    unsigned short* embo = ws;                            // B*256 bf16
    unsigned short* wp2 = embo + (size_t)B * 256;         // 25600
    unsigned short* wp3 = wp2 + 25600;                    // 51200
    unsigned short* wp4 = wp3 + 51200;                    // 102400
    unsigned short* wph1 = wp4 + 102400;                  // 131072
    unsigned short* wpcn2 = wph1 + 131072;                // 32768
    unsigned short* wpep2 = wpcn2 + 32768;                // 12288
    unsigned short* wp1 = wpep2 + 12288;                  // 1024

    k_prepall<<<1392, 256, 0, stream>>>(c1w, c2w, c3w, c4w, cnw1, epw1, cnw2, epw2,
                                        wp1, wp2, wp3, wp4, wph1, wpcn2, wpep2);
    k_convall<<<B, 512, 0, stream>>>(image, c1b, wp1, wp2, c2b, wp3, c3b, wp4, c4b, embo);
    k_heads<<<B / 16, 256, 0, stream>>>(embo, wph1, cnb1, epb1,
                                        wpcn2, cnb2, wpep2, epb2, (float*)d_out);
}